// Round 15
// baseline (241.177 us; speedup 1.0000x reference)
//
#include <hip/hip_runtime.h>
#include <hip/hip_bf16.h>

// Problem constants (from reference)
#define B_   4
#define S_   2048
#define DIN  1024
#define DH   1024
#define DOUT 1024

typedef __attribute__((ext_vector_type(8))) __bf16 bf16x8;
typedef __attribute__((ext_vector_type(4))) float floatx4;
typedef __attribute__((ext_vector_type(4))) float f32x4;     // native vec (nontemporal-legal)
typedef __attribute__((ext_vector_type(4))) int i32x4;
typedef __attribute__((ext_vector_type(4))) u_short u16x4;
typedef unsigned short u16;
typedef unsigned int u32;
typedef unsigned long long u64;

__device__ inline u16 f2bf(float f) {
  union { float f; u32 u; } x; x.f = f;
  u32 r = x.u + 0x7fffu + ((x.u >> 16) & 1u);  // RTNE
  return (u16)(r >> 16);
}

#define GLOAD(SRC, DST) __builtin_amdgcn_global_load_lds(                     \
    (const __attribute__((address_space(1))) u32*)(SRC),                      \
    (__attribute__((address_space(3))) u32*)(DST), 16, 0, 0)
#define WAITVM0() asm volatile("s_waitcnt vmcnt(0)" ::: "memory")

// ---------------------------------------------------------------------------
// wcast: fp32 -> bf16 for the 4 weight matrices only (q/k/v casts are now
// fused into the projection GEMM's A-staging).  4096 single-shot blocks.
// ---------------------------------------------------------------------------
__global__ __launch_bounds__(256)
void wcast(const float* __restrict__ w0, const float* __restrict__ w1,
           const float* __restrict__ w2, const float* __restrict__ w3,
           u16* __restrict__ dst) {
  const long nW = (long)DH * DIN;          // 1,048,576
  long b = blockIdx.x;
  const int r = (int)(b >> 10);            // 1024 blocks per weight
  const float* src = (r == 0) ? w0 : (r == 1) ? w1 : (r == 2) ? w2 : w3;
  long i = (b & 1023) * 256 + threadIdx.x;
  f32x4 vv = __builtin_nontemporal_load(((const f32x4*)src) + i);
  u16x4 o;
  o.x = f2bf(vv.x); o.y = f2bf(vv.y); o.z = f2bf(vv.z); o.w = f2bf(vv.w);
  ((u16x4*)(dst + (long)r * nW))[i] = o;
}

// ---------------------------------------------------------------------------
// mask_pack: int32 mask -> 2MB bitmask, int4 (16B/lane) + 4x __ballot per
// wave-iteration (R12-verified interleaved layout):
//   granule g = 256 consecutive ints -> 4 u64:
//   packed[g*4+j] bit l  <->  mask[g*256 + 4*l + j]
// ---------------------------------------------------------------------------
__global__ __launch_bounds__(256)
void mask_pack(const int* __restrict__ mask, u64* __restrict__ packed) {
  const long f = (long)blockIdx.x * 256 + threadIdx.x;   // int4 index
  i32x4 m4 = __builtin_nontemporal_load(((const i32x4*)mask) + f);
  u64 b0 = __ballot(m4.x != 0);
  u64 b1 = __ballot(m4.y != 0);
  u64 b2 = __ballot(m4.z != 0);
  u64 b3 = __ballot(m4.w != 0);
  if ((threadIdx.x & 63) == 0) {
    const long g = f >> 6;                 // wave-uniform (f base 64-aligned)
    ulonglong2 p01; p01.x = b0; p01.y = b1;
    ulonglong2 p23; p23.x = b2; p23.y = b3;
    ((ulonglong2*)(packed + g * 4))[0] = p01;
    ((ulonglong2*)(packed + g * 4))[1] = p23;
  }
}

// ---------------------------------------------------------------------------
// bf16 32x32-tile transpose (V -> V^T so PV becomes a B^T GEMM)
// ---------------------------------------------------------------------------
__global__ __launch_bounds__(256)
void transpose_bf16(const u16* __restrict__ in, u16* __restrict__ out) {
  __shared__ u16 t[32][33];
  const int b = blockIdx.z;
  const int r0 = blockIdx.y * 32, c0 = blockIdx.x * 32;
  const int tx = threadIdx.x & 31, ty = threadIdx.x >> 5;  // 32 x 8
  const u16* ib = in + (long)b * S_ * DH;
  u16* ob = out + (long)b * DH * S_;
#pragma unroll
  for (int i = 0; i < 4; ++i) {
    int r = ty + i * 8;
    t[r][tx] = ib[(long)(r0 + r) * DH + (c0 + tx)];
  }
  __syncthreads();
#pragma unroll
  for (int i = 0; i < 4; ++i) {
    int r = ty + i * 8;
    ob[(long)(c0 + r) * S_ + (r0 + tx)] = t[tx][r];
  }
}

// ---------------------------------------------------------------------------
// gemm97: m97-replica bf16 B^T GEMM.  C[M,N] = A[M,K] @ B[N,K]^T (+epilogue).
//   BM=BN=128, BK=64, 4 waves (2x2; 64x64 per wave), 16x16x32 MFMA.
//   LDS 32 KB SINGLE buffer, XOR-swizzled slots (T2).
//   AF32=false: A staged via global_load_lds (linear dest, swizzled src).
//   AF32=true (proj): A staged DIRECTLY FROM FP32 -- 8 independent f32x4
//     loads/thread (32B, coalesced: 8 lanes cover one 256B row segment in
//     permuted slot order), compiler cvt_pk to bf16, 4x ds_write_b128 to the
//     SAME linear dest; write slot (tid&7) holds source slot st_ks, so the
//     swizzled reads stay correct.  Kills the 170MB q/k/v cast round-trip.
//   launch_bounds(256,4): 4 blocks/CU resident cover the per-tile drain.
// ---------------------------------------------------------------------------
#define EPI_BF16_BIAS     0   // C u16 : v + bias_{bz}[col]
#define EPI_BF16_ROWSCALE 1   // C u16 : v / rowsum  (rowsum from Psum[.,16])
#define EPI_F32_BIAS      2   // C f32 : v + bias0[col]

template <int EPI, bool AF32>
__global__ __launch_bounds__(256, 4)
void gemm97(const u16* __restrict__ A,
            const float* __restrict__ Af0, const float* __restrict__ Af1,
            const float* __restrict__ Af2,
            const u16* __restrict__ Bm, void* __restrict__ C,
            const float* __restrict__ bias0, const float* __restrict__ bias1,
            const float* __restrict__ bias2,
            const float* __restrict__ Psum,
            int M, int N, int K,
            long sA, long sB, long sC,
            int nbx, int nby) {
  __shared__ u16 lds_[16384];   // A 8192 u16 | B 8192 u16
  __shared__ float invs_s[(EPI == EPI_BF16_ROWSCALE) ? 128 : 1];

  const int tid = threadIdx.x;
  const int w = tid >> 6, l = tid & 63;
  const int wr = w >> 1, wc = w & 1;
  const int lr = l & 15, q = l >> 4;

  // T1 bijective XCD-chunk swizzle (grid % 8 == 0)
  const int flat = blockIdx.x;
  const int swz = (flat & 7) * ((int)gridDim.x >> 3) + (flat >> 3);
  const int bx = swz % nbx;
  const int rest = swz / nbx;
  const int by = rest % nby;
  const int bz = rest / nby;

  const long arow0 = (long)by * 128;
  const long bcol0 = (long)bx * 128;
  const u16* Ab = nullptr;
  const float* Afp = nullptr;
  if constexpr (AF32) {
    const float* As = (bz == 0) ? Af0 : ((bz == 1) ? Af1 : Af2);
    Afp = As + arow0 * K;
  } else {
    Ab = A + bz * sA + arow0 * K;
  }
  const u16* Bb = Bm + bz * sB + bcol0 * K;
  const int nt = K >> 6;

  if constexpr (EPI == EPI_BF16_ROWSCALE) {
    // prologue: invs for this block's 128 rows (64B/thread, coalesced)
    if (tid < 128) {
      const float4* p = (const float4*)(Psum + ((long)bz * S_ + arow0 + tid) * 16);
      float4 a = p[0], b = p[1], c = p[2], d = p[3];
      float s = (a.x + a.y + a.z + a.w) + (b.x + b.y + b.z + b.w)
              + (c.x + c.y + c.z + c.w) + (d.x + d.y + d.z + d.w);
      invs_s[tid] = 1.0f / s;
    }
    // visibility guaranteed by the K-loop barriers before epilogue reads
  }

  const int st_r = tid >> 3;                 // 0..31 row within 32-row group
  const int st_ks = (tid & 7) ^ (st_r & 7);  // swizzled global k-slot

  floatx4 acc[4][4] = {};

  for (int t = 0; t < nt; ++t) {
    const long k0 = (long)t << 6;
    if constexpr (AF32) {
      // A: fp32 reg-staged with conversion (8 loads in flight for MLP)
      f32x4 va[4][2];
#pragma unroll
      for (int i = 0; i < 4; ++i) {
        const float* sp = Afp + (long)(i * 32 + st_r) * K + k0 + st_ks * 8;
        va[i][0] = *(const f32x4*)sp;
        va[i][1] = *(const f32x4*)(sp + 4);
      }
#pragma unroll
      for (int i = 0; i < 4; ++i)
        GLOAD(Bb + (long)(i * 32 + st_r) * K + k0 + st_ks * 8,
              &lds_[8192 + i * 2048 + tid * 8]);
#pragma unroll
      for (int i = 0; i < 4; ++i) {
        bf16x8 o;
#pragma unroll
        for (int j = 0; j < 4; ++j) {
          o[j]     = (__bf16)va[i][0][j];
          o[j + 4] = (__bf16)va[i][1][j];
        }
        *(bf16x8*)&lds_[i * 2048 + tid * 8] = o;
      }
      WAITVM0();       // B gloads landed; ds_writes drained by __syncthreads
    } else {
#pragma unroll
      for (int i = 0; i < 4; ++i)
        GLOAD(Ab + (long)(i * 32 + st_r) * K + k0 + st_ks * 8,
              &lds_[i * 2048 + tid * 8]);
#pragma unroll
      for (int i = 0; i < 4; ++i)
        GLOAD(Bb + (long)(i * 32 + st_r) * K + k0 + st_ks * 8,
              &lds_[8192 + i * 2048 + tid * 8]);
      WAITVM0();       // own stores landed before barrier
    }
    __syncthreads();

    bf16x8 a[4][2], b[4][2];
#pragma unroll
    for (int m = 0; m < 4; ++m)
#pragma unroll
      for (int kk = 0; kk < 2; ++kk) {
        const int r = wr * 64 + m * 16 + lr, s = kk * 4 + q;
        a[m][kk] = *(const bf16x8*)&lds_[r * 64 + ((s ^ (r & 7)) * 8)];
      }
#pragma unroll
    for (int n = 0; n < 4; ++n)
#pragma unroll
      for (int kk = 0; kk < 2; ++kk) {
        const int c = wc * 64 + n * 16 + lr, s = kk * 4 + q;
        b[n][kk] = *(const bf16x8*)&lds_[8192 + c * 64 + ((s ^ (c & 7)) * 8)];
      }
#pragma unroll
    for (int kk = 0; kk < 2; ++kk)
#pragma unroll
      for (int n = 0; n < 4; ++n)
#pragma unroll
        for (int m = 0; m < 4; ++m)
          acc[m][n] = __builtin_amdgcn_mfma_f32_16x16x32_bf16(
              a[m][kk], b[n][kk], acc[m][n], 0, 0, 0);
    __syncthreads();
  }

  // epilogue. C/D layout: col = l&15, row = (l>>4)*4 + reg  [m89]
  const int r4 = q * 4;
  const float* bp = bias0;
  if constexpr (EPI == EPI_BF16_BIAS)
    bp = (bz == 0) ? bias0 : ((bz == 1) ? bias1 : bias2);
#pragma unroll
  for (int mf = 0; mf < 4; ++mf)
#pragma unroll
    for (int nf = 0; nf < 4; ++nf)
#pragma unroll
      for (int r = 0; r < 4; ++r) {
        const long row = arow0 + wr * 64 + mf * 16 + r4 + r;
        const long col = bcol0 + wc * 64 + nf * 16 + lr;
        float v = acc[mf][nf][r];
        if constexpr (EPI == EPI_BF16_BIAS) {
          v += bp[col];
          ((u16*)C)[bz * sC + row * N + col] = f2bf(v);
        } else if constexpr (EPI == EPI_BF16_ROWSCALE) {
          v *= invs_s[wr * 64 + mf * 16 + r4 + r];
          ((u16*)C)[bz * sC + row * N + col] = f2bf(v);
        } else {  // EPI_F32_BIAS
          v += bp[col];
          ((float*)C)[bz * sC + row * N + col] = v;
        }
      }
}

// ---------------------------------------------------------------------------
// pexp128: m97-structure GEMM (K=1024, nt=16) computing
//   P = exp((Q @ K^T)/32) masked->0 (bf16) + per-block row partial sums.
// K-loop is PURE GEMM; mask bits from the 2MB packed bitmask (R12-verified
// interleaved layout + indexing), coop-loaded (2KB) into dead LDS.
// ---------------------------------------------------------------------------
__global__ __launch_bounds__(256, 4)
void pexp128(const u16* __restrict__ Q, const u16* __restrict__ Kb_,
             u16* __restrict__ P, const u32* __restrict__ packed,
             float* __restrict__ Psum) {
  __shared__ u16 lds_[16384];

  const int tid = threadIdx.x;
  const int w = tid >> 6, l = tid & 63;
  const int wr = w >> 1, wc = w & 1;
  const int lr = l & 15, q = l >> 4;

  // T1 swizzle; grid 1024 = nbx16 x nby16 x z4
  const int flat = blockIdx.x;
  const int swz = (flat & 7) * ((int)gridDim.x >> 3) + (flat >> 3);
  const int bx = swz & 15;
  const int rest = swz >> 4;
  const int by = rest & 15;
  const int bz = rest >> 4;

  const long arow0 = (long)by * 128;
  const long bcol0 = (long)bx * 128;
  const int K = DH;
  const u16* Ab = Q + (long)bz * S_ * DH + arow0 * K;
  const u16* Bb = Kb_ + (long)bz * S_ * DH + bcol0 * K;

  const int st_r = tid >> 3;
  const int st_ks = (tid & 7) ^ (st_r & 7);

  floatx4 acc[4][4] = {};

#pragma unroll 4
  for (int t = 0; t < 16; ++t) {
    const long k0 = (long)t << 6;
#pragma unroll
    for (int i = 0; i < 4; ++i)
      GLOAD(Ab + (long)(i * 32 + st_r) * K + k0 + st_ks * 8,
            &lds_[i * 2048 + tid * 8]);
#pragma unroll
    for (int i = 0; i < 4; ++i)
      GLOAD(Bb + (long)(i * 32 + st_r) * K + k0 + st_ks * 8,
            &lds_[8192 + i * 2048 + tid * 8]);
    WAITVM0();
    __syncthreads();

    bf16x8 a[4][2], b[4][2];
#pragma unroll
    for (int m = 0; m < 4; ++m)
#pragma unroll
      for (int kk = 0; kk < 2; ++kk) {
        const int r = wr * 64 + m * 16 + lr, s = kk * 4 + q;
        a[m][kk] = *(const bf16x8*)&lds_[r * 64 + ((s ^ (r & 7)) * 8)];
      }
#pragma unroll
    for (int n = 0; n < 4; ++n)
#pragma unroll
      for (int kk = 0; kk < 2; ++kk) {
        const int c = wc * 64 + n * 16 + lr, s = kk * 4 + q;
        b[n][kk] = *(const bf16x8*)&lds_[8192 + c * 64 + ((s ^ (c & 7)) * 8)];
      }
#pragma unroll
    for (int kk = 0; kk < 2; ++kk)
#pragma unroll
      for (int n = 0; n < 4; ++n)
#pragma unroll
        for (int m = 0; m < 4; ++m)
          acc[m][n] = __builtin_amdgcn_mfma_f32_16x16x32_bf16(
              a[m][kk], b[n][kk], acc[m][n], 0, 0, 0);
    __syncthreads();
  }

  // ---- epilogue.
  // 1) coop-load packed-mask u32 halves (R12-verified): for row arow0+lrow,
  //    j=0..3: pw[lrow*4+j] = packed32[g*8 + j*2 + (bx&1)],
  //    g = bz*16384 + row*8 + (bx>>1).  2KB into dead LDS at byte 16384.
  u32* pw = (u32*)&lds_[8192];    // 512 u32
  {
    const int half = bx & 1;
    const int lrow = tid >> 1;                 // 0..127
    const int j0 = (tid & 1) * 2;              // 0 or 2
    const long g = (long)bz * 16384 + (arow0 + lrow) * 8 + (bx >> 1);
    pw[lrow * 4 + j0]     = packed[g * 8 + j0 * 2 + half];
    pw[lrow * 4 + j0 + 1] = packed[g * 8 + (j0 + 1) * 2 + half];
  }
  __syncthreads();

  // 2) p = bit ? exp(v/32) : 0; bf16 store; row partial sums.
  //    word = pw[lrow*4 + (lr&3)], bit = wc*16 + nf*4 + (lr>>2)  [R12]
  const int r4 = q * 4;
  float rsum[4][4];
#pragma unroll
  for (int mf = 0; mf < 4; ++mf)
#pragma unroll
    for (int r = 0; r < 4; ++r) rsum[mf][r] = 0.f;

#pragma unroll
  for (int mf = 0; mf < 4; ++mf)
#pragma unroll
    for (int r = 0; r < 4; ++r) {
      const int lrow = wr * 64 + mf * 16 + r4 + r;
      const long row = arow0 + lrow;
      const u32 word = pw[lrow * 4 + (lr & 3)];
#pragma unroll
      for (int nf = 0; nf < 4; ++nf) {
        const int bitpos = wc * 16 + nf * 4 + (lr >> 2);
        const long col = bcol0 + wc * 64 + nf * 16 + lr;
        float p = 0.f;
        if ((word >> bitpos) & 1u) p = __expf(acc[mf][nf][r] * 0.03125f);
        P[(long)bz * S_ * S_ + row * S_ + col] = f2bf(p);
        rsum[mf][r] += p;
      }
    }
  __syncthreads();   // all bit-reads done before Psum scratch reuses LDS

  // 3) reduce over the 16 lr-lanes, then across the 2 wc waves via LDS
  float* sc = (float*)lds_;   // [128 rows][2 wc] f32 at byte 0 (disjoint)
#pragma unroll
  for (int mf = 0; mf < 4; ++mf)
#pragma unroll
    for (int r = 0; r < 4; ++r) {
      float s = rsum[mf][r];
      s += __shfl_xor(s, 1); s += __shfl_xor(s, 2);
      s += __shfl_xor(s, 4); s += __shfl_xor(s, 8);
      if (lr == 0) sc[(wr * 64 + mf * 16 + r4 + r) * 2 + wc] = s;
    }
  __syncthreads();
  if (tid < 128) {
    float tot = sc[tid * 2] + sc[tid * 2 + 1];
    Psum[((long)bz * S_ + arow0 + tid) * 16 + bx] = tot;
  }
}

// ---------------------------------------------------------------------------
extern "C" void kernel_launch(void* const* d_in, const int* in_sizes, int n_in,
                              void* d_out, int out_size, void* d_ws, size_t ws_size,
                              hipStream_t stream) {
  const float* q    = (const float*)d_in[0];
  const float* k    = (const float*)d_in[1];
  const float* v    = (const float*)d_in[2];
  const int*   mask = (const int*)d_in[3];
  const float* Wq   = (const float*)d_in[4];
  const float* bq   = (const float*)d_in[5];
  const float* Wk   = (const float*)d_in[6];
  const float* bk   = (const float*)d_in[7];
  const float* Wv   = (const float*)d_in[8];
  const float* bv   = (const float*)d_in[9];
  const float* Wo   = (const float*)d_in[10];
  const float* bo   = (const float*)d_in[11];

  const long BS = (long)B_ * S_;      // 8192
  const long nQ = BS * DH;            // 8,388,608
  const long nW = (long)DH * DIN;     // 1,048,576
  const long nE = (long)B_ * S_ * S_; // 16,777,216

  char* ws = (char*)d_ws;
  size_t off = 0;
  auto alloc = [&](size_t bytes) {
    void* p = ws + off; off += (bytes + 255) & ~(size_t)255; return p;
  };

  u16* wqb  = (u16*)alloc(4 * nW * 2);       // wq|wk|wv|wo contiguous
  u16* Qb   = (u16*)alloc(nQ * 2);           // Qb,Kbf,Vb contiguous (z-batch)
  u16* Kbf  = (u16*)alloc(nQ * 2);
  u16* Vb   = (u16*)alloc(nQ * 2);
  u16* VT   = (u16*)alloc(nQ * 2);
  u16* P    = (u16*)alloc(nE * 2);           // exp(e) unnormalized, bf16
  u64* pk   = (u64*)alloc(nE / 8);           // packed mask bits (2MB)
  float* Psum = (float*)alloc(BS * 16 * 4);  // per-block row partials
  u16* Yb   = (u16*)alloc(nQ * 2);           // attention output
  u16* wob  = wqb + 3 * nW;
  (void)Kbf;

  // 1. weight cast + mask pack (q/k/v casts fused into proj staging)
  wcast<<<dim3(4096), 256, 0, stream>>>(Wq, Wk, Wv, Wo, wqb);
  mask_pack<<<dim3(16384), 256, 0, stream>>>(mask, pk);

  // 2. QKV projections, z=3, A staged directly from fp32: grid 8x64x3 = 1536
  gemm97<EPI_BF16_BIAS, true><<<dim3(1536), 256, 0, stream>>>(
      nullptr, q, k, v, wqb, Qb, bq, bk, bv, nullptr,
      (int)BS, DH, DIN, 0, nW, nQ, 8, 64);

  // 3. V -> V^T per batch
  {
    dim3 g(DH / 32, S_ / 32, B_);
    transpose_bf16<<<g, 256, 0, stream>>>(Vb, VT);
  }

  // 4. P = exp((Q K^T)/32) masked->0 + row partials: grid 16x16x4 = 1024
  pexp128<<<dim3(1024), 256, 0, stream>>>(Qb, Kbf, P, (const u32*)pk, Psum);

  // 5. Y = (P @ V) / rowsum == P[S,S] @ VT[DH,S]^T: grid 8x16x4 = 512
  gemm97<EPI_BF16_ROWSCALE, false><<<dim3(512), 256, 0, stream>>>(
      P, nullptr, nullptr, nullptr, VT, Yb, nullptr, nullptr, nullptr, Psum,
      S_, DH, S_, (long)S_ * S_, (long)DH * S_, (long)S_ * DH, 8, 16);

  // 6. out = Y @ Wo^T + bo -> fp32 d_out: grid 8x64 = 512
  gemm97<EPI_F32_BIAS, false><<<dim3(512), 256, 0, stream>>>(
      Yb, nullptr, nullptr, nullptr, wob, d_out, bo, nullptr, nullptr, nullptr,
      (int)BS, DOUT, DH, 0, 0, 0, 8, 64);
}

// Round 16
// 235.317 us; speedup vs baseline: 1.0249x; 1.0249x over previous
//
#include <hip/hip_runtime.h>
#include <hip/hip_bf16.h>

// Problem constants (from reference)
#define B_   4
#define S_   2048
#define DIN  1024
#define DH   1024
#define DOUT 1024

typedef __attribute__((ext_vector_type(8))) __bf16 bf16x8;
typedef __attribute__((ext_vector_type(4))) float floatx4;
typedef __attribute__((ext_vector_type(4))) float f32x4;   // native vec for nontemporal
typedef __attribute__((ext_vector_type(4))) u_short u16x4;
typedef unsigned short u16;
typedef unsigned int u32;
typedef unsigned long long u64;

__device__ inline u16 f2bf(float f) {
  union { float f; u32 u; } x; x.f = f;
  u32 r = x.u + 0x7fffu + ((x.u >> 16) & 1u);  // RTNE
  return (u16)(r >> 16);
}

#define GLOAD(SRC, DST) __builtin_amdgcn_global_load_lds(                     \
    (const __attribute__((address_space(1))) u32*)(SRC),                      \
    (__attribute__((address_space(3))) u32*)(DST), 16, 0, 0)
#define WAITVM0() asm volatile("s_waitcnt vmcnt(0)" ::: "memory")

// ---------------------------------------------------------------------------
// cast_all: fp32 -> bf16 for q,k,v,Wq,Wk,Wv,Wo (R9/R14-proven single-shot
// shape).  One float4/lane, nontemporal read via native ext_vector_type.
// R15 lesson: fusing this into the GEMM's A-staging (reg-staged fp32) exposes
// cold-HBM latency per tile and costs 3x -- keep the separate streaming pass.
// ---------------------------------------------------------------------------
__global__ __launch_bounds__(256)
void cast_all(const float* __restrict__ q, const float* __restrict__ k,
              const float* __restrict__ v, const float* __restrict__ w0,
              const float* __restrict__ w1, const float* __restrict__ w2,
              const float* __restrict__ w3, u16* __restrict__ dst) {
  const long nQ = (long)B_ * S_ * DIN;   // 8,388,608
  const long nW = (long)DH * DIN;        // 1,048,576
  long b = blockIdx.x;
  const float* src; long doff;
  if (b < 8192)       { src = q;  doff = 0;            }
  else if (b < 16384) { src = k;  doff = nQ;     b -= 8192;  }
  else if (b < 24576) { src = v;  doff = 2 * nQ; b -= 16384; }
  else if (b < 25600) { src = w0; doff = 3 * nQ; b -= 24576; }
  else if (b < 26624) { src = w1; doff = 3 * nQ + nW;     b -= 25600; }
  else if (b < 27648) { src = w2; doff = 3 * nQ + 2 * nW; b -= 26624; }
  else                { src = w3; doff = 3 * nQ + 3 * nW; b -= 27648; }
  long i = b * 256 + threadIdx.x;        // float4 index within region
  f32x4 vv = __builtin_nontemporal_load(((const f32x4*)src) + i);
  u16x4 o;
  o.x = f2bf(vv.x); o.y = f2bf(vv.y); o.z = f2bf(vv.z); o.w = f2bf(vv.w);
  ((u16x4*)(dst + doff))[i] = o;
}

// ---------------------------------------------------------------------------
// mask_pack: int32 mask -> bitmask (R9-proven shape).  Wave reads 64
// consecutive ints (4B/lane, nontemporal), one __ballot, lane 0 stores u64.
// Layout: packed[i>>6] bit l <-> mask[i base + l]  (no interleaving).
// ---------------------------------------------------------------------------
__global__ __launch_bounds__(256)
void mask_pack(const int* __restrict__ mask, u64* __restrict__ packed) {
  const long i = (long)blockIdx.x * 256 + threadIdx.x;
  const int mk = __builtin_nontemporal_load(mask + i);
  const u64 bal = __ballot(mk != 0);
  if ((threadIdx.x & 63) == 0) packed[i >> 6] = bal;
}

// ---------------------------------------------------------------------------
// bf16 32x32-tile transpose (V -> V^T so PV becomes a B^T GEMM)
// ---------------------------------------------------------------------------
__global__ __launch_bounds__(256)
void transpose_bf16(const u16* __restrict__ in, u16* __restrict__ out) {
  __shared__ u16 t[32][33];
  const int b = blockIdx.z;
  const int r0 = blockIdx.y * 32, c0 = blockIdx.x * 32;
  const int tx = threadIdx.x & 31, ty = threadIdx.x >> 5;  // 32 x 8
  const u16* ib = in + (long)b * S_ * DH;
  u16* ob = out + (long)b * DH * S_;
#pragma unroll
  for (int i = 0; i < 4; ++i) {
    int r = ty + i * 8;
    t[r][tx] = ib[(long)(r0 + r) * DH + (c0 + tx)];
  }
  __syncthreads();
#pragma unroll
  for (int i = 0; i < 4; ++i) {
    int r = ty + i * 8;
    ob[(long)(c0 + r) * S_ + (r0 + tx)] = t[tx][r];
  }
}

// ---------------------------------------------------------------------------
// gemm97: m97-replica bf16 B^T GEMM.  C[M,N] = A[M,K] @ B[N,K]^T (+epilogue).
//   BM=BN=128, BK=64, 4 waves (2x2; 64x64 per wave), 16x16x32 MFMA.
//   LDS 32 KB SINGLE buffer, XOR-swizzled slots (T2); staging dest LINEAR
//   (rule 21), global src carries the inverse slot permutation.
//   launch_bounds(256,4): 4 blocks/CU resident cover the per-tile drain
//   (m97/m114 implicit-TLP).  Proven 937 TF (m97-structure ceiling).
//   EPI_BF16_BIAS selects bq/bk/bv by bz; EPI_BF16_ROWSCALE folds the
//   rowsum reduction into a tiny prologue.
// ---------------------------------------------------------------------------
#define EPI_BF16_BIAS     0   // C u16 : v + bias_{bz}[col]
#define EPI_BF16_ROWSCALE 1   // C u16 : v / rowsum  (rowsum from Psum[.,16])
#define EPI_F32_BIAS      2   // C f32 : v + bias0[col]

template <int EPI>
__global__ __launch_bounds__(256, 4)
void gemm97(const u16* __restrict__ A, const u16* __restrict__ Bm,
            void* __restrict__ C,
            const float* __restrict__ bias0, const float* __restrict__ bias1,
            const float* __restrict__ bias2,
            const float* __restrict__ Psum,
            int M, int N, int K,
            long sA, long sB, long sC,
            int nbx, int nby) {
  __shared__ u16 lds_[16384];   // A 8192 u16 | B 8192 u16
  __shared__ float invs_s[(EPI == EPI_BF16_ROWSCALE) ? 128 : 1];

  const int tid = threadIdx.x;
  const int w = tid >> 6, l = tid & 63;
  const int wr = w >> 1, wc = w & 1;
  const int lr = l & 15, q = l >> 4;

  // T1 bijective XCD-chunk swizzle (grid % 8 == 0)
  const int flat = blockIdx.x;
  const int swz = (flat & 7) * ((int)gridDim.x >> 3) + (flat >> 3);
  const int bx = swz % nbx;
  const int rest = swz / nbx;
  const int by = rest % nby;
  const int bz = rest / nby;

  const long arow0 = (long)by * 128;
  const long bcol0 = (long)bx * 128;
  const u16* Ab = A + bz * sA + arow0 * K;
  const u16* Bb = Bm + bz * sB + bcol0 * K;
  const int nt = K >> 6;

  if constexpr (EPI == EPI_BF16_ROWSCALE) {
    // prologue: invs for this block's 128 rows (64B/thread, coalesced)
    if (tid < 128) {
      const float4* p = (const float4*)(Psum + ((long)bz * S_ + arow0 + tid) * 16);
      float4 a = p[0], b = p[1], c = p[2], d = p[3];
      float s = (a.x + a.y + a.z + a.w) + (b.x + b.y + b.z + b.w)
              + (c.x + c.y + c.z + c.w) + (d.x + d.y + d.z + d.w);
      invs_s[tid] = 1.0f / s;
    }
    // visibility guaranteed by the K-loop barriers before epilogue reads
  }

  const int st_r = tid >> 3;                 // 0..31 row within 32-row group
  const int st_ks = (tid & 7) ^ (st_r & 7);  // swizzled global k-slot

  floatx4 acc[4][4] = {};

  for (int t = 0; t < nt; ++t) {
    const long k0 = (long)t << 6;
#pragma unroll
    for (int i = 0; i < 4; ++i)
      GLOAD(Ab + (long)(i * 32 + st_r) * K + k0 + st_ks * 8,
            &lds_[i * 2048 + tid * 8]);
#pragma unroll
    for (int i = 0; i < 4; ++i)
      GLOAD(Bb + (long)(i * 32 + st_r) * K + k0 + st_ks * 8,
            &lds_[8192 + i * 2048 + tid * 8]);
    WAITVM0();         // own stores landed before barrier
    __syncthreads();

    bf16x8 a[4][2], b[4][2];
#pragma unroll
    for (int m = 0; m < 4; ++m)
#pragma unroll
      for (int kk = 0; kk < 2; ++kk) {
        const int r = wr * 64 + m * 16 + lr, s = kk * 4 + q;
        a[m][kk] = *(const bf16x8*)&lds_[r * 64 + ((s ^ (r & 7)) * 8)];
      }
#pragma unroll
    for (int n = 0; n < 4; ++n)
#pragma unroll
      for (int kk = 0; kk < 2; ++kk) {
        const int c = wc * 64 + n * 16 + lr, s = kk * 4 + q;
        b[n][kk] = *(const bf16x8*)&lds_[8192 + c * 64 + ((s ^ (c & 7)) * 8)];
      }
#pragma unroll
    for (int kk = 0; kk < 2; ++kk)
#pragma unroll
      for (int n = 0; n < 4; ++n)
#pragma unroll
        for (int m = 0; m < 4; ++m)
          acc[m][n] = __builtin_amdgcn_mfma_f32_16x16x32_bf16(
              a[m][kk], b[n][kk], acc[m][n], 0, 0, 0);
    __syncthreads();
  }

  // epilogue. C/D layout: col = l&15, row = (l>>4)*4 + reg  [m89]
  const int r4 = q * 4;
  const float* bp = bias0;
  if constexpr (EPI == EPI_BF16_BIAS)
    bp = (bz == 0) ? bias0 : ((bz == 1) ? bias1 : bias2);
#pragma unroll
  for (int mf = 0; mf < 4; ++mf)
#pragma unroll
    for (int nf = 0; nf < 4; ++nf)
#pragma unroll
      for (int r = 0; r < 4; ++r) {
        const long row = arow0 + wr * 64 + mf * 16 + r4 + r;
        const long col = bcol0 + wc * 64 + nf * 16 + lr;
        float v = acc[mf][nf][r];
        if constexpr (EPI == EPI_BF16_BIAS) {
          v += bp[col];
          ((u16*)C)[bz * sC + row * N + col] = f2bf(v);
        } else if constexpr (EPI == EPI_BF16_ROWSCALE) {
          v *= invs_s[wr * 64 + mf * 16 + r4 + r];
          ((u16*)C)[bz * sC + row * N + col] = f2bf(v);
        } else {  // EPI_F32_BIAS
          v += bp[col];
          ((float*)C)[bz * sC + row * N + col] = v;
        }
      }
}

// ---------------------------------------------------------------------------
// pexp128: m97-structure GEMM (K=1024, nt=16) computing
//   P = exp((Q @ K^T)/32) masked->0 (bf16) + per-block row partial sums.
// K-loop is PURE GEMM (R8 lesson: no cold-HBM loads chained into the
// per-tile drain); mask bits come from the 2MB packed bitmask (R9 layout:
// packed[i>>6] bit l <-> mask int i), coop-loaded (2KB) into dead LDS in
// the epilogue.  R9/R14-verified bit indexing.
// ---------------------------------------------------------------------------
__global__ __launch_bounds__(256, 4)
void pexp128(const u16* __restrict__ Q, const u16* __restrict__ Kb_,
             u16* __restrict__ P, const u32* __restrict__ packed,
             float* __restrict__ Psum) {
  __shared__ u16 lds_[16384];

  const int tid = threadIdx.x;
  const int w = tid >> 6, l = tid & 63;
  const int wr = w >> 1, wc = w & 1;
  const int lr = l & 15, q = l >> 4;

  // T1 swizzle; grid 1024 = nbx16 x nby16 x z4
  const int flat = blockIdx.x;
  const int swz = (flat & 7) * ((int)gridDim.x >> 3) + (flat >> 3);
  const int bx = swz & 15;
  const int rest = swz >> 4;
  const int by = rest & 15;
  const int bz = rest >> 4;

  const long arow0 = (long)by * 128;
  const long bcol0 = (long)bx * 128;
  const int K = DH;
  const u16* Ab = Q + (long)bz * S_ * DH + arow0 * K;
  const u16* Bb = Kb_ + (long)bz * S_ * DH + bcol0 * K;

  const int st_r = tid >> 3;
  const int st_ks = (tid & 7) ^ (st_r & 7);

  floatx4 acc[4][4] = {};

#pragma unroll 4
  for (int t = 0; t < 16; ++t) {
    const long k0 = (long)t << 6;
#pragma unroll
    for (int i = 0; i < 4; ++i)
      GLOAD(Ab + (long)(i * 32 + st_r) * K + k0 + st_ks * 8,
            &lds_[i * 2048 + tid * 8]);
#pragma unroll
    for (int i = 0; i < 4; ++i)
      GLOAD(Bb + (long)(i * 32 + st_r) * K + k0 + st_ks * 8,
            &lds_[8192 + i * 2048 + tid * 8]);
    WAITVM0();
    __syncthreads();

    bf16x8 a[4][2], b[4][2];
#pragma unroll
    for (int m = 0; m < 4; ++m)
#pragma unroll
      for (int kk = 0; kk < 2; ++kk) {
        const int r = wr * 64 + m * 16 + lr, s = kk * 4 + q;
        a[m][kk] = *(const bf16x8*)&lds_[r * 64 + ((s ^ (r & 7)) * 8)];
      }
#pragma unroll
    for (int n = 0; n < 4; ++n)
#pragma unroll
      for (int kk = 0; kk < 2; ++kk) {
        const int c = wc * 64 + n * 16 + lr, s = kk * 4 + q;
        b[n][kk] = *(const bf16x8*)&lds_[8192 + c * 64 + ((s ^ (c & 7)) * 8)];
      }
#pragma unroll
    for (int kk = 0; kk < 2; ++kk)
#pragma unroll
      for (int n = 0; n < 4; ++n)
#pragma unroll
        for (int m = 0; m < 4; ++m)
          acc[m][n] = __builtin_amdgcn_mfma_f32_16x16x32_bf16(
              a[m][kk], b[n][kk], acc[m][n], 0, 0, 0);
    __syncthreads();
  }

  // ---- epilogue.
  // 1) coop-load the block's packed mask words: 128 rows x 4 u32 = 2KB into
  //    dead LDS at byte 16384.. (disjoint from Psum scratch at byte 0).
  u32* pw = (u32*)&lds_[8192];    // 512 u32
  {
    const u32* pg = packed + (long)bz * S_ * (S_ / 32)
                  + arow0 * (S_ / 32) + (bcol0 >> 5);
    const int lrow = tid >> 1;                 // 0..127
    const int j0 = (tid & 1) * 2;              // 0 or 2
    pw[lrow * 4 + j0]     = pg[(long)lrow * (S_ / 32) + j0];
    pw[lrow * 4 + j0 + 1] = pg[(long)lrow * (S_ / 32) + j0 + 1];
  }
  __syncthreads();

  // 2) p = bit ? exp(v/32) : 0; bf16 store; row partial sums.
  //    word = pw[lrow*4 + wc*2 + (nf>>1)], bit = (nf&1)*16 + lr  [R9-verified]
  const int r4 = q * 4;
  float rsum[4][4];
#pragma unroll
  for (int mf = 0; mf < 4; ++mf)
#pragma unroll
    for (int r = 0; r < 4; ++r) rsum[mf][r] = 0.f;

#pragma unroll
  for (int mf = 0; mf < 4; ++mf)
#pragma unroll
    for (int r = 0; r < 4; ++r) {
      const int lrow = wr * 64 + mf * 16 + r4 + r;
      const long row = arow0 + lrow;
#pragma unroll
      for (int nf = 0; nf < 4; ++nf) {
        const u32 word = pw[lrow * 4 + wc * 2 + (nf >> 1)];
        const int bitpos = (nf & 1) * 16 + lr;
        const long col = bcol0 + wc * 64 + nf * 16 + lr;
        float p = 0.f;
        if ((word >> bitpos) & 1u) p = __expf(acc[mf][nf][r] * 0.03125f);
        P[(long)bz * S_ * S_ + row * S_ + col] = f2bf(p);
        rsum[mf][r] += p;
      }
    }
  __syncthreads();   // all bit-reads done before Psum scratch reuses LDS

  // 3) reduce over the 16 lr-lanes, then across the 2 wc waves via LDS
  float* sc = (float*)lds_;   // [128 rows][2 wc] f32 at byte 0 (disjoint)
#pragma unroll
  for (int mf = 0; mf < 4; ++mf)
#pragma unroll
    for (int r = 0; r < 4; ++r) {
      float s = rsum[mf][r];
      s += __shfl_xor(s, 1); s += __shfl_xor(s, 2);
      s += __shfl_xor(s, 4); s += __shfl_xor(s, 8);
      if (lr == 0) sc[(wr * 64 + mf * 16 + r4 + r) * 2 + wc] = s;
    }
  __syncthreads();
  if (tid < 128) {
    float tot = sc[tid * 2] + sc[tid * 2 + 1];
    Psum[((long)bz * S_ + arow0 + tid) * 16 + bx] = tot;
  }
}

// ---------------------------------------------------------------------------
extern "C" void kernel_launch(void* const* d_in, const int* in_sizes, int n_in,
                              void* d_out, int out_size, void* d_ws, size_t ws_size,
                              hipStream_t stream) {
  const float* q    = (const float*)d_in[0];
  const float* k    = (const float*)d_in[1];
  const float* v    = (const float*)d_in[2];
  const int*   mask = (const int*)d_in[3];
  const float* Wq   = (const float*)d_in[4];
  const float* bq   = (const float*)d_in[5];
  const float* Wk   = (const float*)d_in[6];
  const float* bk   = (const float*)d_in[7];
  const float* Wv   = (const float*)d_in[8];
  const float* bv   = (const float*)d_in[9];
  const float* Wo   = (const float*)d_in[10];
  const float* bo   = (const float*)d_in[11];

  const long BS = (long)B_ * S_;      // 8192
  const long nQ = BS * DH;            // 8,388,608
  const long nW = (long)DH * DIN;     // 1,048,576
  const long nE = (long)B_ * S_ * S_; // 16,777,216

  char* ws = (char*)d_ws;
  size_t off = 0;
  auto alloc = [&](size_t bytes) {
    void* p = ws + off; off += (bytes + 255) & ~(size_t)255; return p;
  };

  // NOTE: qb..wob must stay CONTIGUOUS in this order (cast_all assumes it);
  // Qb,Kbf,Vb contiguous (proj z-batch output).
  u16* qb   = (u16*)alloc(nQ * 2);
  u16* kb   = (u16*)alloc(nQ * 2);
  u16* vb   = (u16*)alloc(nQ * 2);
  u16* wqb  = (u16*)alloc(nW * 2);
  u16* wkb  = (u16*)alloc(nW * 2);
  u16* wvb  = (u16*)alloc(nW * 2);
  u16* wob  = (u16*)alloc(nW * 2);
  u16* Qb   = (u16*)alloc(nQ * 2);
  u16* Kbf  = (u16*)alloc(nQ * 2);
  u16* Vb   = (u16*)alloc(nQ * 2);
  u16* VT   = (u16*)alloc(nQ * 2);
  u16* P    = (u16*)alloc(nE * 2);           // exp(e) unnormalized, bf16
  u64* pk   = (u64*)alloc(nE / 8);           // packed mask bits (2MB)
  float* Psum = (float*)alloc(BS * 16 * 4);  // per-block row partials
  u16* Yb  = vb;  // attention output aliases vb (consumed by proj)
  (void)kb; (void)wkb; (void)wvb;

  // 1. casts + mask pack (separate kernels: proven fast shapes)
  cast_all<<<dim3(28672), 256, 0, stream>>>(q, k, v, Wq, Wk, Wv, Wo, qb);
  mask_pack<<<dim3(65536), 256, 0, stream>>>(mask, pk);

  // 2. QKV projections, z=3: grid 8x64x3 = 1536 (bias selected by bz)
  gemm97<EPI_BF16_BIAS><<<dim3(1536), 256, 0, stream>>>(qb, wqb, Qb,
      bq, bk, bv, nullptr, (int)BS, DH, DIN, nQ, nW, nQ, 8, 64);

  // 3. V -> V^T per batch
  {
    dim3 g(DH / 32, S_ / 32, B_);
    transpose_bf16<<<g, 256, 0, stream>>>(Vb, VT);
  }

  // 4. P = exp((Q K^T)/32) masked->0 + row partials: grid 16x16x4 = 1024
  pexp128<<<dim3(1024), 256, 0, stream>>>(Qb, Kbf, P, (const u32*)pk, Psum);

  // 5. Y = (P @ V) / rowsum == P[S,S] @ VT[DH,S]^T: grid 8x16x4 = 512
  //    (rowsum reduction folded into the kernel prologue from Psum)
  gemm97<EPI_BF16_ROWSCALE><<<dim3(512), 256, 0, stream>>>(P, VT, Yb,
      nullptr, nullptr, nullptr, Psum, S_, DH, S_,
      (long)S_ * S_, (long)DH * S_, (long)S_ * DH, 8, 16);

  // 6. out = Y @ Wo^T + bo -> fp32 d_out: grid 8x64 = 512
  gemm97<EPI_F32_BIAS><<<dim3(512), 256, 0, stream>>>(Yb, wob, d_out,
      bo, nullptr, nullptr, nullptr, (int)BS, DOUT, DH, 0, 0, 0, 8, 64);
}

// Round 17
// 227.861 us; speedup vs baseline: 1.0584x; 1.0327x over previous
//
#include <hip/hip_runtime.h>
#include <hip/hip_bf16.h>

// Problem constants (from reference)
#define B_   4
#define S_   2048
#define DIN  1024
#define DH   1024
#define DOUT 1024

typedef __attribute__((ext_vector_type(8))) __bf16 bf16x8;
typedef __attribute__((ext_vector_type(4))) float floatx4;
typedef __attribute__((ext_vector_type(4))) float f32x4;   // native vec for nontemporal
typedef __attribute__((ext_vector_type(4))) u_short u16x4;
typedef unsigned short u16;
typedef unsigned int u32;
typedef unsigned long long u64;

__device__ inline u16 f2bf(float f) {
  union { float f; u32 u; } x; x.f = f;
  u32 r = x.u + 0x7fffu + ((x.u >> 16) & 1u);  // RTNE
  return (u16)(r >> 16);
}

#define GLOAD(SRC, DST) __builtin_amdgcn_global_load_lds(                     \
    (const __attribute__((address_space(1))) u32*)(SRC),                      \
    (__attribute__((address_space(3))) u32*)(DST), 16, 0, 0)
#define WAITVM0() asm volatile("s_waitcnt vmcnt(0)" ::: "memory")

// ---------------------------------------------------------------------------
// wcast: fp32 -> bf16 for the 4 weight matrices only (q/k/v now consumed
// directly in fp32 by the projection GEMM's LDS staging).  R15-proven shape.
// ---------------------------------------------------------------------------
__global__ __launch_bounds__(256)
void wcast(const float* __restrict__ w0, const float* __restrict__ w1,
           const float* __restrict__ w2, const float* __restrict__ w3,
           u16* __restrict__ dst) {
  const long nW = (long)DH * DIN;          // 1,048,576
  long b = blockIdx.x;
  const int r = (int)(b >> 10);            // 1024 blocks per weight
  const float* src = (r == 0) ? w0 : (r == 1) ? w1 : (r == 2) ? w2 : w3;
  long i = (b & 1023) * 256 + threadIdx.x;
  f32x4 vv = __builtin_nontemporal_load(((const f32x4*)src) + i);
  u16x4 o;
  o.x = f2bf(vv.x); o.y = f2bf(vv.y); o.z = f2bf(vv.z); o.w = f2bf(vv.w);
  ((u16x4*)(dst + (long)r * nW))[i] = o;
}

// ---------------------------------------------------------------------------
// mask_pack: int32 mask -> bitmask (R9/R14-proven shape).  Wave reads 64
// consecutive ints (4B/lane, nontemporal), one __ballot, lane 0 stores u64.
// Layout: packed[i>>6] bit l <-> mask[i base + l].
// ---------------------------------------------------------------------------
__global__ __launch_bounds__(256)
void mask_pack(const int* __restrict__ mask, u64* __restrict__ packed) {
  const long i = (long)blockIdx.x * 256 + threadIdx.x;
  const int mk = __builtin_nontemporal_load(mask + i);
  const u64 bal = __ballot(mk != 0);
  if ((threadIdx.x & 63) == 0) packed[i >> 6] = bal;
}

// ---------------------------------------------------------------------------
// bf16 32x32-tile transpose (V -> V^T so PV becomes a B^T GEMM)
// ---------------------------------------------------------------------------
__global__ __launch_bounds__(256)
void transpose_bf16(const u16* __restrict__ in, u16* __restrict__ out) {
  __shared__ u16 t[32][33];
  const int b = blockIdx.z;
  const int r0 = blockIdx.y * 32, c0 = blockIdx.x * 32;
  const int tx = threadIdx.x & 31, ty = threadIdx.x >> 5;  // 32 x 8
  const u16* ib = in + (long)b * S_ * DH;
  u16* ob = out + (long)b * DH * S_;
#pragma unroll
  for (int i = 0; i < 4; ++i) {
    int r = ty + i * 8;
    t[r][tx] = ib[(long)(r0 + r) * DH + (c0 + tx)];
  }
  __syncthreads();
#pragma unroll
  for (int i = 0; i < 4; ++i) {
    int r = ty + i * 8;
    ob[(long)(c0 + r) * S_ + (r0 + tx)] = t[tx][r];
  }
}

// ---------------------------------------------------------------------------
// gemm97f: m97-structure GEMM with A staged DIRECTLY FROM FP32 via
// global_load_lds (fire-and-forget DMA -- NOT R15's reg-staging, whose
// load->wait->ds_write chain exposed cold-HBM latency per tile).
//   A LDS tile: fp32 [128 rows][64 k] = 32 KB; 8 gloads/thread/tile.
//     dest (linear, rule 21): round i -> u16 idx i*2048 + tid*8
//       == (i*16 + tid>>4)*128 + (tid&15)*8  (wave-check: base + 8*l ✓)
//     src (swizzled): row = i*16 + (tid>>4), chunk = (tid&15) ^ (row&15)
//       -> 16 lanes cover a 256B row-span, permuted (all 64B lines full).
//   LDS->reg: fragment (r, s8=kk*4+q) reads fp32 chunks (2s8)^(r&15),
//     (2s8+1)^(r&15) as two ds_read_b128 (banks = c' mod 8, 16 distinct c'
//     -> 2-way alias = free), then (__bf16) casts (compiler cvt_pk).
//   B: bf16 global_load_lds path unchanged (region base 16384 u16).
//   LDS 48 KB -> launch_bounds(256,3): 3 resident blocks/CU (R9-proven 55us
//   at this occupancy).  Saves cast_all's 170MB q/k/v round-trip.
// ---------------------------------------------------------------------------
__global__ __launch_bounds__(256, 3)
void gemm97f(const float* __restrict__ Af0, const float* __restrict__ Af1,
             const float* __restrict__ Af2,
             const u16* __restrict__ Bm, u16* __restrict__ C,
             const float* __restrict__ bias0, const float* __restrict__ bias1,
             const float* __restrict__ bias2,
             int M, int N, int K, long sB, long sC,
             int nbx, int nby) {
  __shared__ u16 lds_[24576];   // A fp32 [0,16384) u16 | B bf16 [16384,24576)

  const int tid = threadIdx.x;
  const int w = tid >> 6, l = tid & 63;
  const int wr = w >> 1, wc = w & 1;
  const int lr = l & 15, q = l >> 4;

  // T1 bijective XCD-chunk swizzle (grid % 8 == 0)
  const int flat = blockIdx.x;
  const int swz = (flat & 7) * ((int)gridDim.x >> 3) + (flat >> 3);
  const int bx = swz % nbx;
  const int rest = swz / nbx;
  const int by = rest % nby;
  const int bz = rest / nby;

  const long arow0 = (long)by * 128;
  const long bcol0 = (long)bx * 128;
  const float* As = (bz == 0) ? Af0 : ((bz == 1) ? Af1 : Af2);
  const float* Afp = As + arow0 * K;
  const u16* Bb = Bm + bz * sB + bcol0 * K;
  const int nt = K >> 6;

  // A staging per-thread constants
  const int stA_r = tid >> 4;                   // 0..15 row in 16-row group
  const int stA_c = tid & 15;                   // 16B chunk id (4 f32)
  // B staging per-thread constants (bf16 path, as before)
  const int stB_r = tid >> 3;
  const int stB_ks = (tid & 7) ^ (stB_r & 7);

  floatx4 acc[4][4] = {};

  for (int t = 0; t < nt; ++t) {
    const long k0 = (long)t << 6;               // in elements (f32 or bf16)
#pragma unroll
    for (int i = 0; i < 8; ++i) {               // A: fp32, 32 KB
      const int row = i * 16 + stA_r;
      const int csw = stA_c ^ (row & 15);
      GLOAD(Afp + (long)row * K + k0 + csw * 4,
            &lds_[i * 2048 + tid * 8]);
    }
#pragma unroll
    for (int i = 0; i < 4; ++i)                 // B: bf16, 16 KB
      GLOAD(Bb + (long)(i * 32 + stB_r) * K + k0 + stB_ks * 8,
            &lds_[16384 + i * 2048 + tid * 8]);
    WAITVM0();
    __syncthreads();

    bf16x8 a[4][2], b[4][2];
#pragma unroll
    for (int m = 0; m < 4; ++m)
#pragma unroll
      for (int kk = 0; kk < 2; ++kk) {
        const int r = wr * 64 + m * 16 + lr;
        const int s8 = kk * 4 + q;
        const int c0 = (2 * s8) ^ (r & 15);
        const int c1 = (2 * s8 + 1) ^ (r & 15);
        f32x4 lo = *(const f32x4*)&lds_[r * 128 + c0 * 8];
        f32x4 hi = *(const f32x4*)&lds_[r * 128 + c1 * 8];
        bf16x8 o;
#pragma unroll
        for (int j = 0; j < 4; ++j) {
          o[j]     = (__bf16)lo[j];
          o[j + 4] = (__bf16)hi[j];
        }
        a[m][kk] = o;
      }
#pragma unroll
    for (int n = 0; n < 4; ++n)
#pragma unroll
      for (int kk = 0; kk < 2; ++kk) {
        const int c = wc * 64 + n * 16 + lr, s = kk * 4 + q;
        b[n][kk] = *(const bf16x8*)&lds_[16384 + c * 64 + ((s ^ (c & 7)) * 8)];
      }
#pragma unroll
    for (int kk = 0; kk < 2; ++kk)
#pragma unroll
      for (int n = 0; n < 4; ++n)
#pragma unroll
        for (int m = 0; m < 4; ++m)
          acc[m][n] = __builtin_amdgcn_mfma_f32_16x16x32_bf16(
              a[m][kk], b[n][kk], acc[m][n], 0, 0, 0);
    __syncthreads();
  }

  // epilogue. C/D layout: col = l&15, row = (l>>4)*4 + reg  [m89]
  const int r4 = q * 4;
  const float* bp = (bz == 0) ? bias0 : ((bz == 1) ? bias1 : bias2);
#pragma unroll
  for (int mf = 0; mf < 4; ++mf)
#pragma unroll
    for (int nf = 0; nf < 4; ++nf)
#pragma unroll
      for (int r = 0; r < 4; ++r) {
        const long row = arow0 + wr * 64 + mf * 16 + r4 + r;
        const long col = bcol0 + wc * 64 + nf * 16 + lr;
        float v = acc[mf][nf][r] + bp[col];
        C[bz * sC + row * N + col] = f2bf(v);
      }
}

// ---------------------------------------------------------------------------
// gemm97: m97-replica bf16 B^T GEMM (unchanged, proven 937 TF).
//   BM=BN=128, BK=64, 4 waves, 32 KB LDS, XOR-swizzled, (256,4).
// ---------------------------------------------------------------------------
#define EPI_BF16_ROWSCALE 1   // C u16 : v / rowsum  (rowsum from Psum[.,16])
#define EPI_F32_BIAS      2   // C f32 : v + bias0[col]

template <int EPI>
__global__ __launch_bounds__(256, 4)
void gemm97(const u16* __restrict__ A, const u16* __restrict__ Bm,
            void* __restrict__ C,
            const float* __restrict__ bias0,
            const float* __restrict__ Psum,
            int M, int N, int K,
            long sA, long sB, long sC,
            int nbx, int nby) {
  __shared__ u16 lds_[16384];   // A 8192 u16 | B 8192 u16
  __shared__ float invs_s[(EPI == EPI_BF16_ROWSCALE) ? 128 : 1];

  const int tid = threadIdx.x;
  const int w = tid >> 6, l = tid & 63;
  const int wr = w >> 1, wc = w & 1;
  const int lr = l & 15, q = l >> 4;

  // T1 bijective XCD-chunk swizzle (grid % 8 == 0)
  const int flat = blockIdx.x;
  const int swz = (flat & 7) * ((int)gridDim.x >> 3) + (flat >> 3);
  const int bx = swz % nbx;
  const int rest = swz / nbx;
  const int by = rest % nby;
  const int bz = rest / nby;

  const long arow0 = (long)by * 128;
  const long bcol0 = (long)bx * 128;
  const u16* Ab = A + bz * sA + arow0 * K;
  const u16* Bb = Bm + bz * sB + bcol0 * K;
  const int nt = K >> 6;

  if constexpr (EPI == EPI_BF16_ROWSCALE) {
    if (tid < 128) {
      const float4* p = (const float4*)(Psum + ((long)bz * S_ + arow0 + tid) * 16);
      float4 a = p[0], b = p[1], c = p[2], d = p[3];
      float s = (a.x + a.y + a.z + a.w) + (b.x + b.y + b.z + b.w)
              + (c.x + c.y + c.z + c.w) + (d.x + d.y + d.z + d.w);
      invs_s[tid] = 1.0f / s;
    }
  }

  const int st_r = tid >> 3;
  const int st_ks = (tid & 7) ^ (st_r & 7);

  floatx4 acc[4][4] = {};

  for (int t = 0; t < nt; ++t) {
    const long k0 = (long)t << 6;
#pragma unroll
    for (int i = 0; i < 4; ++i)
      GLOAD(Ab + (long)(i * 32 + st_r) * K + k0 + st_ks * 8,
            &lds_[i * 2048 + tid * 8]);
#pragma unroll
    for (int i = 0; i < 4; ++i)
      GLOAD(Bb + (long)(i * 32 + st_r) * K + k0 + st_ks * 8,
            &lds_[8192 + i * 2048 + tid * 8]);
    WAITVM0();
    __syncthreads();

    bf16x8 a[4][2], b[4][2];
#pragma unroll
    for (int m = 0; m < 4; ++m)
#pragma unroll
      for (int kk = 0; kk < 2; ++kk) {
        const int r = wr * 64 + m * 16 + lr, s = kk * 4 + q;
        a[m][kk] = *(const bf16x8*)&lds_[r * 64 + ((s ^ (r & 7)) * 8)];
      }
#pragma unroll
    for (int n = 0; n < 4; ++n)
#pragma unroll
      for (int kk = 0; kk < 2; ++kk) {
        const int c = wc * 64 + n * 16 + lr, s = kk * 4 + q;
        b[n][kk] = *(const bf16x8*)&lds_[8192 + c * 64 + ((s ^ (c & 7)) * 8)];
      }
#pragma unroll
    for (int kk = 0; kk < 2; ++kk)
#pragma unroll
      for (int n = 0; n < 4; ++n)
#pragma unroll
        for (int m = 0; m < 4; ++m)
          acc[m][n] = __builtin_amdgcn_mfma_f32_16x16x32_bf16(
              a[m][kk], b[n][kk], acc[m][n], 0, 0, 0);
    __syncthreads();
  }

  const int r4 = q * 4;
#pragma unroll
  for (int mf = 0; mf < 4; ++mf)
#pragma unroll
    for (int nf = 0; nf < 4; ++nf)
#pragma unroll
      for (int r = 0; r < 4; ++r) {
        const long row = arow0 + wr * 64 + mf * 16 + r4 + r;
        const long col = bcol0 + wc * 64 + nf * 16 + lr;
        float v = acc[mf][nf][r];
        if constexpr (EPI == EPI_BF16_ROWSCALE) {
          v *= invs_s[wr * 64 + mf * 16 + r4 + r];
          ((u16*)C)[bz * sC + row * N + col] = f2bf(v);
        } else {  // EPI_F32_BIAS
          v += bias0[col];
          ((float*)C)[bz * sC + row * N + col] = v;
        }
      }
}

// ---------------------------------------------------------------------------
// pexp128: m97-structure GEMM (K=1024, nt=16) computing
//   P = exp((Q @ K^T)/32) masked->0 (bf16) + per-block row partial sums.
// Pure-GEMM K-loop; mask bits from the 2MB packed bitmask (R9 layout),
// coop-loaded (2KB) into dead LDS.  R9/R14/R16-verified.
// ---------------------------------------------------------------------------
__global__ __launch_bounds__(256, 4)
void pexp128(const u16* __restrict__ Q, const u16* __restrict__ Kb_,
             u16* __restrict__ P, const u32* __restrict__ packed,
             float* __restrict__ Psum) {
  __shared__ u16 lds_[16384];

  const int tid = threadIdx.x;
  const int w = tid >> 6, l = tid & 63;
  const int wr = w >> 1, wc = w & 1;
  const int lr = l & 15, q = l >> 4;

  // T1 swizzle; grid 1024 = nbx16 x nby16 x z4
  const int flat = blockIdx.x;
  const int swz = (flat & 7) * ((int)gridDim.x >> 3) + (flat >> 3);
  const int bx = swz & 15;
  const int rest = swz >> 4;
  const int by = rest & 15;
  const int bz = rest >> 4;

  const long arow0 = (long)by * 128;
  const long bcol0 = (long)bx * 128;
  const int K = DH;
  const u16* Ab = Q + (long)bz * S_ * DH + arow0 * K;
  const u16* Bb = Kb_ + (long)bz * S_ * DH + bcol0 * K;

  const int st_r = tid >> 3;
  const int st_ks = (tid & 7) ^ (st_r & 7);

  floatx4 acc[4][4] = {};

#pragma unroll 4
  for (int t = 0; t < 16; ++t) {
    const long k0 = (long)t << 6;
#pragma unroll
    for (int i = 0; i < 4; ++i)
      GLOAD(Ab + (long)(i * 32 + st_r) * K + k0 + st_ks * 8,
            &lds_[i * 2048 + tid * 8]);
#pragma unroll
    for (int i = 0; i < 4; ++i)
      GLOAD(Bb + (long)(i * 32 + st_r) * K + k0 + st_ks * 8,
            &lds_[8192 + i * 2048 + tid * 8]);
    WAITVM0();
    __syncthreads();

    bf16x8 a[4][2], b[4][2];
#pragma unroll
    for (int m = 0; m < 4; ++m)
#pragma unroll
      for (int kk = 0; kk < 2; ++kk) {
        const int r = wr * 64 + m * 16 + lr, s = kk * 4 + q;
        a[m][kk] = *(const bf16x8*)&lds_[r * 64 + ((s ^ (r & 7)) * 8)];
      }
#pragma unroll
    for (int n = 0; n < 4; ++n)
#pragma unroll
      for (int kk = 0; kk < 2; ++kk) {
        const int c = wc * 64 + n * 16 + lr, s = kk * 4 + q;
        b[n][kk] = *(const bf16x8*)&lds_[8192 + c * 64 + ((s ^ (c & 7)) * 8)];
      }
#pragma unroll
    for (int kk = 0; kk < 2; ++kk)
#pragma unroll
      for (int n = 0; n < 4; ++n)
#pragma unroll
        for (int m = 0; m < 4; ++m)
          acc[m][n] = __builtin_amdgcn_mfma_f32_16x16x32_bf16(
              a[m][kk], b[n][kk], acc[m][n], 0, 0, 0);
    __syncthreads();
  }

  // ---- epilogue.
  u32* pw = (u32*)&lds_[8192];    // 512 u32 (dead LDS)
  {
    const u32* pg = packed + (long)bz * S_ * (S_ / 32)
                  + arow0 * (S_ / 32) + (bcol0 >> 5);
    const int lrow = tid >> 1;
    const int j0 = (tid & 1) * 2;
    pw[lrow * 4 + j0]     = pg[(long)lrow * (S_ / 32) + j0];
    pw[lrow * 4 + j0 + 1] = pg[(long)lrow * (S_ / 32) + j0 + 1];
  }
  __syncthreads();

  const int r4 = q * 4;
  float rsum[4][4];
#pragma unroll
  for (int mf = 0; mf < 4; ++mf)
#pragma unroll
    for (int r = 0; r < 4; ++r) rsum[mf][r] = 0.f;

#pragma unroll
  for (int mf = 0; mf < 4; ++mf)
#pragma unroll
    for (int r = 0; r < 4; ++r) {
      const int lrow = wr * 64 + mf * 16 + r4 + r;
      const long row = arow0 + lrow;
#pragma unroll
      for (int nf = 0; nf < 4; ++nf) {
        const u32 word = pw[lrow * 4 + wc * 2 + (nf >> 1)];
        const int bitpos = (nf & 1) * 16 + lr;
        const long col = bcol0 + wc * 64 + nf * 16 + lr;
        float p = 0.f;
        if ((word >> bitpos) & 1u) p = __expf(acc[mf][nf][r] * 0.03125f);
        P[(long)bz * S_ * S_ + row * S_ + col] = f2bf(p);
        rsum[mf][r] += p;
      }
    }
  __syncthreads();

  float* sc = (float*)lds_;
#pragma unroll
  for (int mf = 0; mf < 4; ++mf)
#pragma unroll
    for (int r = 0; r < 4; ++r) {
      float s = rsum[mf][r];
      s += __shfl_xor(s, 1); s += __shfl_xor(s, 2);
      s += __shfl_xor(s, 4); s += __shfl_xor(s, 8);
      if (lr == 0) sc[(wr * 64 + mf * 16 + r4 + r) * 2 + wc] = s;
    }
  __syncthreads();
  if (tid < 128) {
    float tot = sc[tid * 2] + sc[tid * 2 + 1];
    Psum[((long)bz * S_ + arow0 + tid) * 16 + bx] = tot;
  }
}

// ---------------------------------------------------------------------------
extern "C" void kernel_launch(void* const* d_in, const int* in_sizes, int n_in,
                              void* d_out, int out_size, void* d_ws, size_t ws_size,
                              hipStream_t stream) {
  const float* q    = (const float*)d_in[0];
  const float* k    = (const float*)d_in[1];
  const float* v    = (const float*)d_in[2];
  const int*   mask = (const int*)d_in[3];
  const float* Wq   = (const float*)d_in[4];
  const float* bq   = (const float*)d_in[5];
  const float* Wk   = (const float*)d_in[6];
  const float* bk   = (const float*)d_in[7];
  const float* Wv   = (const float*)d_in[8];
  const float* bv   = (const float*)d_in[9];
  const float* Wo   = (const float*)d_in[10];
  const float* bo   = (const float*)d_in[11];

  const long BS = (long)B_ * S_;      // 8192
  const long nQ = BS * DH;            // 8,388,608
  const long nW = (long)DH * DIN;     // 1,048,576
  const long nE = (long)B_ * S_ * S_; // 16,777,216

  char* ws = (char*)d_ws;
  size_t off = 0;
  auto alloc = [&](size_t bytes) {
    void* p = ws + off; off += (bytes + 255) & ~(size_t)255; return p;
  };

  u16* wqb  = (u16*)alloc(4 * nW * 2);       // wq|wk|wv|wo contiguous
  u16* Qb   = (u16*)alloc(nQ * 2);           // Qb,Kbf,Vb contiguous (z-batch)
  u16* Kbf  = (u16*)alloc(nQ * 2);
  u16* Vb   = (u16*)alloc(nQ * 2);
  u16* VT   = (u16*)alloc(nQ * 2);
  u16* P    = (u16*)alloc(nE * 2);           // exp(e) unnormalized, bf16
  u64* pk   = (u64*)alloc(nE / 8);           // packed mask bits (2MB)
  float* Psum = (float*)alloc(BS * 16 * 4);  // per-block row partials
  u16* Yb   = (u16*)alloc(nQ * 2);           // attention output
  u16* wob  = wqb + 3 * nW;

  // 1. weight cast + mask pack (q/k/v consumed in fp32 by proj staging)
  wcast<<<dim3(4096), 256, 0, stream>>>(Wq, Wk, Wv, Wo, wqb);
  mask_pack<<<dim3(65536), 256, 0, stream>>>(mask, pk);

  // 2. QKV projections, z=3, A staged from fp32 via global_load_lds:
  //    grid 8x64x3 = 1536
  gemm97f<<<dim3(1536), 256, 0, stream>>>(q, k, v, wqb, Qb, bq, bk, bv,
      (int)BS, DH, DIN, nW, nQ, 8, 64);

  // 3. V -> V^T per batch
  {
    dim3 g(DH / 32, S_ / 32, B_);
    transpose_bf16<<<g, 256, 0, stream>>>(Vb, VT);
  }

  // 4. P = exp((Q K^T)/32) masked->0 + row partials: grid 16x16x4 = 1024
  pexp128<<<dim3(1024), 256, 0, stream>>>(Qb, Kbf, P, (const u32*)pk, Psum);

  // 5. Y = (P @ V) / rowsum == P[S,S] @ VT[DH,S]^T: grid 8x16x4 = 512
  gemm97<EPI_BF16_ROWSCALE><<<dim3(512), 256, 0, stream>>>(P, VT, Yb,
      nullptr, Psum, S_, DH, S_,
      (long)S_ * S_, (long)DH * S_, (long)S_ * DH, 8, 16);

  // 6. out = Y @ Wo^T + bo -> fp32 d_out: grid 8x64 = 512
  gemm97<EPI_F32_BIAS><<<dim3(512), 256, 0, stream>>>(Yb, wob, d_out,
      bo, nullptr, (int)BS, DOUT, DH, 0, 0, 0, 8, 64);
}

// Round 18
// 212.993 us; speedup vs baseline: 1.1323x; 1.0698x over previous
//
#include <hip/hip_runtime.h>
#include <hip/hip_bf16.h>

// Problem constants (from reference)
#define B_   4
#define S_   2048
#define DIN  1024
#define DH   1024
#define DOUT 1024

typedef __attribute__((ext_vector_type(8))) __bf16 bf16x8;
typedef __attribute__((ext_vector_type(4))) float floatx4;
typedef __attribute__((ext_vector_type(4))) float f32x4;   // native vec for nontemporal
typedef __attribute__((ext_vector_type(4))) int i32x4;
typedef __attribute__((ext_vector_type(4))) u_short u16x4;
typedef unsigned short u16;
typedef unsigned int u32;
typedef unsigned long long u64;

__device__ inline u16 f2bf(float f) {
  union { float f; u32 u; } x; x.f = f;
  u32 r = x.u + 0x7fffu + ((x.u >> 16) & 1u);  // RTNE
  return (u16)(r >> 16);
}

#define GLOAD(SRC, DST) __builtin_amdgcn_global_load_lds(                     \
    (const __attribute__((address_space(1))) u32*)(SRC),                      \
    (__attribute__((address_space(3))) u32*)(DST), 16, 0, 0)
#define WAITVM0() asm volatile("s_waitcnt vmcnt(0)" ::: "memory")

// ---------------------------------------------------------------------------
// wcast: fp32 -> bf16 for the 4 weight matrices only (q/k/v consumed
// directly in fp32 by the projection GEMM's LDS staging).  R15/R17-proven.
// ---------------------------------------------------------------------------
__global__ __launch_bounds__(256)
void wcast(const float* __restrict__ w0, const float* __restrict__ w1,
           const float* __restrict__ w2, const float* __restrict__ w3,
           u16* __restrict__ dst) {
  const long nW = (long)DH * DIN;          // 1,048,576
  long b = blockIdx.x;
  const int r = (int)(b >> 10);            // 1024 blocks per weight
  const float* src = (r == 0) ? w0 : (r == 1) ? w1 : (r == 2) ? w2 : w3;
  long i = (b & 1023) * 256 + threadIdx.x;
  f32x4 vv = __builtin_nontemporal_load(((const f32x4*)src) + i);
  u16x4 o;
  o.x = f2bf(vv.x); o.y = f2bf(vv.y); o.z = f2bf(vv.z); o.w = f2bf(vv.w);
  ((u16x4*)(dst + (long)r * nW))[i] = o;
}

// ---------------------------------------------------------------------------
// mask_pack: int32 mask -> 2MB bitmask.  int4 (16B/lane) + 4x __ballot per
// wave (R12/R15-verified interleaved layout):
//   granule g = 256 consecutive ints -> 4 u64:
//   packed[g*4+j] bit l  <->  mask[g*256 + 4*l + j]
// 16384 blocks (4x fewer waves, 4x bytes/inst vs the scalar variant).
// ---------------------------------------------------------------------------
__global__ __launch_bounds__(256)
void mask_pack(const int* __restrict__ mask, u64* __restrict__ packed) {
  const long f = (long)blockIdx.x * 256 + threadIdx.x;   // int4 index
  i32x4 m4 = __builtin_nontemporal_load(((const i32x4*)mask) + f);
  u64 b0 = __ballot(m4.x != 0);
  u64 b1 = __ballot(m4.y != 0);
  u64 b2 = __ballot(m4.z != 0);
  u64 b3 = __ballot(m4.w != 0);
  if ((threadIdx.x & 63) == 0) {
    const long g = f >> 6;                 // wave-uniform (f base 64-aligned)
    ulonglong2 p01; p01.x = b0; p01.y = b1;
    ulonglong2 p23; p23.x = b2; p23.y = b3;
    ((ulonglong2*)(packed + g * 4))[0] = p01;
    ((ulonglong2*)(packed + g * 4))[1] = p23;
  }
}

// ---------------------------------------------------------------------------
// bf16 32x32-tile transpose (V -> V^T so PV becomes a B^T GEMM)
// ---------------------------------------------------------------------------
__global__ __launch_bounds__(256)
void transpose_bf16(const u16* __restrict__ in, u16* __restrict__ out) {
  __shared__ u16 t[32][33];
  const int b = blockIdx.z;
  const int r0 = blockIdx.y * 32, c0 = blockIdx.x * 32;
  const int tx = threadIdx.x & 31, ty = threadIdx.x >> 5;  // 32 x 8
  const u16* ib = in + (long)b * S_ * DH;
  u16* ob = out + (long)b * DH * S_;
#pragma unroll
  for (int i = 0; i < 4; ++i) {
    int r = ty + i * 8;
    t[r][tx] = ib[(long)(r0 + r) * DH + (c0 + tx)];
  }
  __syncthreads();
#pragma unroll
  for (int i = 0; i < 4; ++i) {
    int r = ty + i * 8;
    ob[(long)(c0 + r) * S_ + (r0 + tx)] = t[tx][r];
  }
}

// ---------------------------------------------------------------------------
// gemm97f: m97-structure GEMM with A staged DIRECTLY FROM FP32 via
// global_load_lds (fire-and-forget DMA; R17-proven -- best total despite
// per-dispatch counters, since it deletes the 170MB cast round-trip).
//   A LDS tile fp32 [128][64] = 32 KB (8 gloads/thr); B bf16 16 KB.
//   LDS->reg converts fp32->bf16 on the read path (compiler cvt_pk).
//   48 KB LDS -> launch_bounds(256,3).
// ---------------------------------------------------------------------------
__global__ __launch_bounds__(256, 3)
void gemm97f(const float* __restrict__ Af0, const float* __restrict__ Af1,
             const float* __restrict__ Af2,
             const u16* __restrict__ Bm, u16* __restrict__ C,
             const float* __restrict__ bias0, const float* __restrict__ bias1,
             const float* __restrict__ bias2,
             int M, int N, int K, long sB, long sC,
             int nbx, int nby) {
  __shared__ u16 lds_[24576];   // A fp32 [0,16384) u16 | B bf16 [16384,24576)

  const int tid = threadIdx.x;
  const int w = tid >> 6, l = tid & 63;
  const int wr = w >> 1, wc = w & 1;
  const int lr = l & 15, q = l >> 4;

  // T1 bijective XCD-chunk swizzle (grid % 8 == 0)
  const int flat = blockIdx.x;
  const int swz = (flat & 7) * ((int)gridDim.x >> 3) + (flat >> 3);
  const int bx = swz % nbx;
  const int rest = swz / nbx;
  const int by = rest % nby;
  const int bz = rest / nby;

  const long arow0 = (long)by * 128;
  const long bcol0 = (long)bx * 128;
  const float* As = (bz == 0) ? Af0 : ((bz == 1) ? Af1 : Af2);
  const float* Afp = As + arow0 * K;
  const u16* Bb = Bm + bz * sB + bcol0 * K;
  const int nt = K >> 6;

  const int stA_r = tid >> 4;                   // 0..15 row in 16-row group
  const int stA_c = tid & 15;                   // 16B chunk id (4 f32)
  const int stB_r = tid >> 3;
  const int stB_ks = (tid & 7) ^ (stB_r & 7);

  floatx4 acc[4][4] = {};

  for (int t = 0; t < nt; ++t) {
    const long k0 = (long)t << 6;               // elements (f32 or bf16)
#pragma unroll
    for (int i = 0; i < 8; ++i) {               // A: fp32, 32 KB
      const int row = i * 16 + stA_r;
      const int csw = stA_c ^ (row & 15);
      GLOAD(Afp + (long)row * K + k0 + csw * 4,
            &lds_[i * 2048 + tid * 8]);
    }
#pragma unroll
    for (int i = 0; i < 4; ++i)                 // B: bf16, 16 KB
      GLOAD(Bb + (long)(i * 32 + stB_r) * K + k0 + stB_ks * 8,
            &lds_[16384 + i * 2048 + tid * 8]);
    WAITVM0();
    __syncthreads();

    bf16x8 a[4][2], b[4][2];
#pragma unroll
    for (int m = 0; m < 4; ++m)
#pragma unroll
      for (int kk = 0; kk < 2; ++kk) {
        const int r = wr * 64 + m * 16 + lr;
        const int s8 = kk * 4 + q;
        const int c0 = (2 * s8) ^ (r & 15);
        const int c1 = (2 * s8 + 1) ^ (r & 15);
        f32x4 lo = *(const f32x4*)&lds_[r * 128 + c0 * 8];
        f32x4 hi = *(const f32x4*)&lds_[r * 128 + c1 * 8];
        bf16x8 o;
#pragma unroll
        for (int j = 0; j < 4; ++j) {
          o[j]     = (__bf16)lo[j];
          o[j + 4] = (__bf16)hi[j];
        }
        a[m][kk] = o;
      }
#pragma unroll
    for (int n = 0; n < 4; ++n)
#pragma unroll
      for (int kk = 0; kk < 2; ++kk) {
        const int c = wc * 64 + n * 16 + lr, s = kk * 4 + q;
        b[n][kk] = *(const bf16x8*)&lds_[16384 + c * 64 + ((s ^ (c & 7)) * 8)];
      }
#pragma unroll
    for (int kk = 0; kk < 2; ++kk)
#pragma unroll
      for (int n = 0; n < 4; ++n)
#pragma unroll
        for (int m = 0; m < 4; ++m)
          acc[m][n] = __builtin_amdgcn_mfma_f32_16x16x32_bf16(
              a[m][kk], b[n][kk], acc[m][n], 0, 0, 0);
    __syncthreads();
  }

  // epilogue. C/D layout: col = l&15, row = (l>>4)*4 + reg  [m89]
  const int r4 = q * 4;
  const float* bp = (bz == 0) ? bias0 : ((bz == 1) ? bias1 : bias2);
#pragma unroll
  for (int mf = 0; mf < 4; ++mf)
#pragma unroll
    for (int nf = 0; nf < 4; ++nf)
#pragma unroll
      for (int r = 0; r < 4; ++r) {
        const long row = arow0 + wr * 64 + mf * 16 + r4 + r;
        const long col = bcol0 + wc * 64 + nf * 16 + lr;
        float v = acc[mf][nf][r] + bp[col];
        C[bz * sC + row * N + col] = f2bf(v);
      }
}

// ---------------------------------------------------------------------------
// gemm97: m97-replica bf16 B^T GEMM (proven 937 TF).  32 KB LDS, (256,4).
// ---------------------------------------------------------------------------
#define EPI_BF16_ROWSCALE 1   // C u16 : v / rowsum  (rowsum from Psum[.,16])
#define EPI_F32_BIAS      2   // C f32 : v + bias0[col]

template <int EPI>
__global__ __launch_bounds__(256, 4)
void gemm97(const u16* __restrict__ A, const u16* __restrict__ Bm,
            void* __restrict__ C,
            const float* __restrict__ bias0,
            const float* __restrict__ Psum,
            int M, int N, int K,
            long sA, long sB, long sC,
            int nbx, int nby) {
  __shared__ u16 lds_[16384];   // A 8192 u16 | B 8192 u16
  __shared__ float invs_s[(EPI == EPI_BF16_ROWSCALE) ? 128 : 1];

  const int tid = threadIdx.x;
  const int w = tid >> 6, l = tid & 63;
  const int wr = w >> 1, wc = w & 1;
  const int lr = l & 15, q = l >> 4;

  // T1 bijective XCD-chunk swizzle (grid % 8 == 0)
  const int flat = blockIdx.x;
  const int swz = (flat & 7) * ((int)gridDim.x >> 3) + (flat >> 3);
  const int bx = swz % nbx;
  const int rest = swz / nbx;
  const int by = rest % nby;
  const int bz = rest / nby;

  const long arow0 = (long)by * 128;
  const long bcol0 = (long)bx * 128;
  const u16* Ab = A + bz * sA + arow0 * K;
  const u16* Bb = Bm + bz * sB + bcol0 * K;
  const int nt = K >> 6;

  if constexpr (EPI == EPI_BF16_ROWSCALE) {
    if (tid < 128) {
      const float4* p = (const float4*)(Psum + ((long)bz * S_ + arow0 + tid) * 16);
      float4 a = p[0], b = p[1], c = p[2], d = p[3];
      float s = (a.x + a.y + a.z + a.w) + (b.x + b.y + b.z + b.w)
              + (c.x + c.y + c.z + c.w) + (d.x + d.y + d.z + d.w);
      invs_s[tid] = 1.0f / s;
    }
  }

  const int st_r = tid >> 3;
  const int st_ks = (tid & 7) ^ (st_r & 7);

  floatx4 acc[4][4] = {};

  for (int t = 0; t < nt; ++t) {
    const long k0 = (long)t << 6;
#pragma unroll
    for (int i = 0; i < 4; ++i)
      GLOAD(Ab + (long)(i * 32 + st_r) * K + k0 + st_ks * 8,
            &lds_[i * 2048 + tid * 8]);
#pragma unroll
    for (int i = 0; i < 4; ++i)
      GLOAD(Bb + (long)(i * 32 + st_r) * K + k0 + st_ks * 8,
            &lds_[8192 + i * 2048 + tid * 8]);
    WAITVM0();
    __syncthreads();

    bf16x8 a[4][2], b[4][2];
#pragma unroll
    for (int m = 0; m < 4; ++m)
#pragma unroll
      for (int kk = 0; kk < 2; ++kk) {
        const int r = wr * 64 + m * 16 + lr, s = kk * 4 + q;
        a[m][kk] = *(const bf16x8*)&lds_[r * 64 + ((s ^ (r & 7)) * 8)];
      }
#pragma unroll
    for (int n = 0; n < 4; ++n)
#pragma unroll
      for (int kk = 0; kk < 2; ++kk) {
        const int c = wc * 64 + n * 16 + lr, s = kk * 4 + q;
        b[n][kk] = *(const bf16x8*)&lds_[8192 + c * 64 + ((s ^ (c & 7)) * 8)];
      }
#pragma unroll
    for (int kk = 0; kk < 2; ++kk)
#pragma unroll
      for (int n = 0; n < 4; ++n)
#pragma unroll
        for (int m = 0; m < 4; ++m)
          acc[m][n] = __builtin_amdgcn_mfma_f32_16x16x32_bf16(
              a[m][kk], b[n][kk], acc[m][n], 0, 0, 0);
    __syncthreads();
  }

  const int r4 = q * 4;
#pragma unroll
  for (int mf = 0; mf < 4; ++mf)
#pragma unroll
    for (int nf = 0; nf < 4; ++nf)
#pragma unroll
      for (int r = 0; r < 4; ++r) {
        const long row = arow0 + wr * 64 + mf * 16 + r4 + r;
        const long col = bcol0 + wc * 64 + nf * 16 + lr;
        float v = acc[mf][nf][r];
        if constexpr (EPI == EPI_BF16_ROWSCALE) {
          v *= invs_s[wr * 64 + mf * 16 + r4 + r];
          ((u16*)C)[bz * sC + row * N + col] = f2bf(v);
        } else {  // EPI_F32_BIAS
          v += bias0[col];
          ((float*)C)[bz * sC + row * N + col] = v;
        }
      }
}

// ---------------------------------------------------------------------------
// pexp128: m97-structure GEMM (K=1024, nt=16) computing
//   P = exp((Q @ K^T)/32) masked->0 (bf16) + per-block row partial sums.
// Pure-GEMM K-loop; mask bits from the 2MB packed bitmask (R12/R15-verified
// interleaved layout + indexing), coop-loaded (2KB) into dead LDS.
// ---------------------------------------------------------------------------
__global__ __launch_bounds__(256, 4)
void pexp128(const u16* __restrict__ Q, const u16* __restrict__ Kb_,
             u16* __restrict__ P, const u32* __restrict__ packed,
             float* __restrict__ Psum) {
  __shared__ u16 lds_[16384];

  const int tid = threadIdx.x;
  const int w = tid >> 6, l = tid & 63;
  const int wr = w >> 1, wc = w & 1;
  const int lr = l & 15, q = l >> 4;

  // T1 swizzle; grid 1024 = nbx16 x nby16 x z4
  const int flat = blockIdx.x;
  const int swz = (flat & 7) * ((int)gridDim.x >> 3) + (flat >> 3);
  const int bx = swz & 15;
  const int rest = swz >> 4;
  const int by = rest & 15;
  const int bz = rest >> 4;

  const long arow0 = (long)by * 128;
  const long bcol0 = (long)bx * 128;
  const int K = DH;
  const u16* Ab = Q + (long)bz * S_ * DH + arow0 * K;
  const u16* Bb = Kb_ + (long)bz * S_ * DH + bcol0 * K;

  const int st_r = tid >> 3;
  const int st_ks = (tid & 7) ^ (st_r & 7);

  floatx4 acc[4][4] = {};

#pragma unroll 4
  for (int t = 0; t < 16; ++t) {
    const long k0 = (long)t << 6;
#pragma unroll
    for (int i = 0; i < 4; ++i)
      GLOAD(Ab + (long)(i * 32 + st_r) * K + k0 + st_ks * 8,
            &lds_[i * 2048 + tid * 8]);
#pragma unroll
    for (int i = 0; i < 4; ++i)
      GLOAD(Bb + (long)(i * 32 + st_r) * K + k0 + st_ks * 8,
            &lds_[8192 + i * 2048 + tid * 8]);
    WAITVM0();
    __syncthreads();

    bf16x8 a[4][2], b[4][2];
#pragma unroll
    for (int m = 0; m < 4; ++m)
#pragma unroll
      for (int kk = 0; kk < 2; ++kk) {
        const int r = wr * 64 + m * 16 + lr, s = kk * 4 + q;
        a[m][kk] = *(const bf16x8*)&lds_[r * 64 + ((s ^ (r & 7)) * 8)];
      }
#pragma unroll
    for (int n = 0; n < 4; ++n)
#pragma unroll
      for (int kk = 0; kk < 2; ++kk) {
        const int c = wc * 64 + n * 16 + lr, s = kk * 4 + q;
        b[n][kk] = *(const bf16x8*)&lds_[8192 + c * 64 + ((s ^ (c & 7)) * 8)];
      }
#pragma unroll
    for (int kk = 0; kk < 2; ++kk)
#pragma unroll
      for (int n = 0; n < 4; ++n)
#pragma unroll
        for (int m = 0; m < 4; ++m)
          acc[m][n] = __builtin_amdgcn_mfma_f32_16x16x32_bf16(
              a[m][kk], b[n][kk], acc[m][n], 0, 0, 0);
    __syncthreads();
  }

  // ---- epilogue.
  // 1) coop-load packed-mask u32 halves (R12/R15-verified): for row
  //    arow0+lrow, j=0..3: pw[lrow*4+j] = packed32[g*8 + j*2 + (bx&1)],
  //    g = bz*16384 + row*8 + (bx>>1).  2KB into dead LDS.
  u32* pw = (u32*)&lds_[8192];    // 512 u32
  {
    const int half = bx & 1;
    const int lrow = tid >> 1;                 // 0..127
    const int j0 = (tid & 1) * 2;              // 0 or 2
    const long g = (long)bz * 16384 + (arow0 + lrow) * 8 + (bx >> 1);
    pw[lrow * 4 + j0]     = packed[g * 8 + j0 * 2 + half];
    pw[lrow * 4 + j0 + 1] = packed[g * 8 + (j0 + 1) * 2 + half];
  }
  __syncthreads();

  // 2) p = bit ? exp(v/32) : 0; bf16 store; row partial sums.
  //    word = pw[lrow*4 + (lr&3)], bit = wc*16 + nf*4 + (lr>>2)  [R12/R15]
  const int r4 = q * 4;
  float rsum[4][4];
#pragma unroll
  for (int mf = 0; mf < 4; ++mf)
#pragma unroll
    for (int r = 0; r < 4; ++r) rsum[mf][r] = 0.f;

#pragma unroll
  for (int mf = 0; mf < 4; ++mf)
#pragma unroll
    for (int r = 0; r < 4; ++r) {
      const int lrow = wr * 64 + mf * 16 + r4 + r;
      const long row = arow0 + lrow;
      const u32 word = pw[lrow * 4 + (lr & 3)];
#pragma unroll
      for (int nf = 0; nf < 4; ++nf) {
        const int bitpos = wc * 16 + nf * 4 + (lr >> 2);
        const long col = bcol0 + wc * 64 + nf * 16 + lr;
        float p = 0.f;
        if ((word >> bitpos) & 1u) p = __expf(acc[mf][nf][r] * 0.03125f);
        P[(long)bz * S_ * S_ + row * S_ + col] = f2bf(p);
        rsum[mf][r] += p;
      }
    }
  __syncthreads();   // all bit-reads done before Psum scratch reuses LDS

  // 3) reduce over the 16 lr-lanes, then across the 2 wc waves via LDS
  float* sc = (float*)lds_;
#pragma unroll
  for (int mf = 0; mf < 4; ++mf)
#pragma unroll
    for (int r = 0; r < 4; ++r) {
      float s = rsum[mf][r];
      s += __shfl_xor(s, 1); s += __shfl_xor(s, 2);
      s += __shfl_xor(s, 4); s += __shfl_xor(s, 8);
      if (lr == 0) sc[(wr * 64 + mf * 16 + r4 + r) * 2 + wc] = s;
    }
  __syncthreads();
  if (tid < 128) {
    float tot = sc[tid * 2] + sc[tid * 2 + 1];
    Psum[((long)bz * S_ + arow0 + tid) * 16 + bx] = tot;
  }
}

// ---------------------------------------------------------------------------
extern "C" void kernel_launch(void* const* d_in, const int* in_sizes, int n_in,
                              void* d_out, int out_size, void* d_ws, size_t ws_size,
                              hipStream_t stream) {
  const float* q    = (const float*)d_in[0];
  const float* k    = (const float*)d_in[1];
  const float* v    = (const float*)d_in[2];
  const int*   mask = (const int*)d_in[3];
  const float* Wq   = (const float*)d_in[4];
  const float* bq   = (const float*)d_in[5];
  const float* Wk   = (const float*)d_in[6];
  const float* bk   = (const float*)d_in[7];
  const float* Wv   = (const float*)d_in[8];
  const float* bv   = (const float*)d_in[9];
  const float* Wo   = (const float*)d_in[10];
  const float* bo   = (const float*)d_in[11];

  const long BS = (long)B_ * S_;      // 8192
  const long nQ = BS * DH;            // 8,388,608
  const long nW = (long)DH * DIN;     // 1,048,576
  const long nE = (long)B_ * S_ * S_; // 16,777,216

  char* ws = (char*)d_ws;
  size_t off = 0;
  auto alloc = [&](size_t bytes) {
    void* p = ws + off; off += (bytes + 255) & ~(size_t)255; return p;
  };

  u16* wqb  = (u16*)alloc(4 * nW * 2);       // wq|wk|wv|wo contiguous
  u16* Qb   = (u16*)alloc(nQ * 2);           // Qb,Kbf,Vb contiguous (z-batch)
  u16* Kbf  = (u16*)alloc(nQ * 2);
  u16* Vb   = (u16*)alloc(nQ * 2);
  u16* VT   = (u16*)alloc(nQ * 2);
  u16* P    = (u16*)alloc(nE * 2);           // exp(e) unnormalized, bf16
  u64* pk   = (u64*)alloc(nE / 8);           // packed mask bits (2MB)
  float* Psum = (float*)alloc(BS * 16 * 4);  // per-block row partials
  u16* Yb   = (u16*)alloc(nQ * 2);           // attention output
  u16* wob  = wqb + 3 * nW;

  // 1. weight cast + mask pack (q/k/v consumed in fp32 by proj staging)
  wcast<<<dim3(4096), 256, 0, stream>>>(Wq, Wk, Wv, Wo, wqb);
  mask_pack<<<dim3(16384), 256, 0, stream>>>(mask, pk);

  // 2. QKV projections, z=3, A staged from fp32 via global_load_lds:
  //    grid 8x64x3 = 1536
  gemm97f<<<dim3(1536), 256, 0, stream>>>(q, k, v, wqb, Qb, bq, bk, bv,
      (int)BS, DH, DIN, nW, nQ, 8, 64);

  // 3. V -> V^T per batch
  {
    dim3 g(DH / 32, S_ / 32, B_);
    transpose_bf16<<<g, 256, 0, stream>>>(Vb, VT);
  }

  // 4. P = exp((Q K^T)/32) masked->0 + row partials: grid 16x16x4 = 1024
  pexp128<<<dim3(1024), 256, 0, stream>>>(Qb, Kbf, P, (const u32*)pk, Psum);

  // 5. Y = (P @ V) / rowsum == P[S,S] @ VT[DH,S]^T: grid 8x16x4 = 512
  gemm97<EPI_BF16_ROWSCALE><<<dim3(512), 256, 0, stream>>>(P, VT, Yb,
      nullptr, Psum, S_, DH, S_,
      (long)S_ * S_, (long)DH * S_, (long)S_ * DH, 8, 16);

  // 6. out = Y @ Wo^T + bo -> fp32 d_out: grid 8x64 = 512
  gemm97<EPI_F32_BIAS><<<dim3(512), 256, 0, stream>>>(Yb, wob, d_out,
      bo, nullptr, (int)BS, DOUT, DH, 0, 0, 0, 8, 64);
}

// Round 20
// 200.902 us; speedup vs baseline: 1.2005x; 1.0602x over previous
//
#include <hip/hip_runtime.h>
#include <hip/hip_bf16.h>

// Problem constants (from reference)
#define B_   4
#define S_   2048
#define DIN  1024
#define DH   1024
#define DOUT 1024

typedef __attribute__((ext_vector_type(8))) __bf16 bf16x8;
typedef __attribute__((ext_vector_type(4))) float floatx4;
typedef __attribute__((ext_vector_type(4))) float f32x4;   // native vec for nontemporal
typedef __attribute__((ext_vector_type(4))) int i32x4;
typedef __attribute__((ext_vector_type(4))) u_short u16x4;
typedef __attribute__((ext_vector_type(8))) u_short u16x8;
typedef unsigned short u16;
typedef unsigned int u32;
typedef unsigned long long u64;

__device__ inline u16 f2bf(float f) {
  union { float f; u32 u; } x; x.f = f;
  u32 r = x.u + 0x7fffu + ((x.u >> 16) & 1u);  // RTNE
  return (u16)(r >> 16);
}

#define GLOAD(SRC, DST) __builtin_amdgcn_global_load_lds(                     \
    (const __attribute__((address_space(1))) u32*)(SRC),                      \
    (__attribute__((address_space(3))) u32*)(DST), 16, 0, 0)
#define WAITVM0() asm volatile("s_waitcnt vmcnt(0)" ::: "memory")

// ---------------------------------------------------------------------------
// wcast: fp32 -> bf16 for the 4 weight matrices only.  R15/R17-proven.
// ---------------------------------------------------------------------------
__global__ __launch_bounds__(256)
void wcast(const float* __restrict__ w0, const float* __restrict__ w1,
           const float* __restrict__ w2, const float* __restrict__ w3,
           u16* __restrict__ dst) {
  const long nW = (long)DH * DIN;          // 1,048,576
  long b = blockIdx.x;
  const int r = (int)(b >> 10);            // 1024 blocks per weight
  const float* src = (r == 0) ? w0 : (r == 1) ? w1 : (r == 2) ? w2 : w3;
  long i = (b & 1023) * 256 + threadIdx.x;
  f32x4 vv = __builtin_nontemporal_load(((const f32x4*)src) + i);
  u16x4 o;
  o.x = f2bf(vv.x); o.y = f2bf(vv.y); o.z = f2bf(vv.z); o.w = f2bf(vv.w);
  ((u16x4*)(dst + (long)r * nW))[i] = o;
}

// ---------------------------------------------------------------------------
// mask_pack: int32 mask -> 2MB bitmask.  int4 (16B/lane) + 4x __ballot per
// wave (R12/R15/R18-verified interleaved layout):
//   granule g = 256 consecutive ints -> 4 u64:
//   packed[g*4+j] bit l  <->  mask[g*256 + 4*l + j]
// ---------------------------------------------------------------------------
__global__ __launch_bounds__(256)
void mask_pack(const int* __restrict__ mask, u64* __restrict__ packed) {
  const long f = (long)blockIdx.x * 256 + threadIdx.x;   // int4 index
  i32x4 m4 = __builtin_nontemporal_load(((const i32x4*)mask) + f);
  u64 b0 = __ballot(m4.x != 0);
  u64 b1 = __ballot(m4.y != 0);
  u64 b2 = __ballot(m4.z != 0);
  u64 b3 = __ballot(m4.w != 0);
  if ((threadIdx.x & 63) == 0) {
    const long g = f >> 6;                 // wave-uniform (f base 64-aligned)
    ulonglong2 p01; p01.x = b0; p01.y = b1;
    ulonglong2 p23; p23.x = b2; p23.y = b3;
    ((ulonglong2*)(packed + g * 4))[0] = p01;
    ((ulonglong2*)(packed + g * 4))[1] = p23;
  }
}

// ---------------------------------------------------------------------------
// gemm97f: m97-structure GEMM with A staged DIRECTLY FROM FP32 via
// global_load_lds (R17-proven net win).  A fp32 32 KB + B bf16 16 KB LDS,
// launch_bounds(256,3).  For bz==2 (V projection) the epilogue writes V^T
// directly: per-wave 64x64 transpose through the dead LDS (pad-68 rows),
// coalesced 16B stores.  R19 BUGFIX: V^T index is batch-major
// b*DH*S + col*S + s (was col*S + global_row -- scattered batches 1-3);
// blocks never straddle batch boundaries (128 | 2048) so b = arow0>>11.
// Added explicit __syncthreads() between transpose LDS write and read.
// ---------------------------------------------------------------------------
__global__ __launch_bounds__(256, 3)
void gemm97f(const float* __restrict__ Af0, const float* __restrict__ Af1,
             const float* __restrict__ Af2,
             const u16* __restrict__ Bm, u16* __restrict__ C,
             u16* __restrict__ VT,
             const float* __restrict__ bias0, const float* __restrict__ bias1,
             const float* __restrict__ bias2,
             int M, int N, int K, long sB, long sC,
             int nbx, int nby) {
  __shared__ u16 lds_[24576];   // A fp32 [0,16384) u16 | B bf16 [16384,24576)

  const int tid = threadIdx.x;
  const int w = tid >> 6, l = tid & 63;
  const int wr = w >> 1, wc = w & 1;
  const int lr = l & 15, q = l >> 4;

  // T1 bijective XCD-chunk swizzle (grid % 8 == 0)
  const int flat = blockIdx.x;
  const int swz = (flat & 7) * ((int)gridDim.x >> 3) + (flat >> 3);
  const int bx = swz % nbx;
  const int rest = swz / nbx;
  const int by = rest % nby;
  const int bz = rest / nby;

  const long arow0 = (long)by * 128;
  const long bcol0 = (long)bx * 128;
  const float* As = (bz == 0) ? Af0 : ((bz == 1) ? Af1 : Af2);
  const float* Afp = As + arow0 * K;
  const u16* Bb = Bm + bz * sB + bcol0 * K;
  const int nt = K >> 6;

  const int stA_r = tid >> 4;                   // 0..15 row in 16-row group
  const int stA_c = tid & 15;                   // 16B chunk id (4 f32)
  const int stB_r = tid >> 3;
  const int stB_ks = (tid & 7) ^ (stB_r & 7);

  floatx4 acc[4][4] = {};

  for (int t = 0; t < nt; ++t) {
    const long k0 = (long)t << 6;               // elements (f32 or bf16)
#pragma unroll
    for (int i = 0; i < 8; ++i) {               // A: fp32, 32 KB
      const int row = i * 16 + stA_r;
      const int csw = stA_c ^ (row & 15);
      GLOAD(Afp + (long)row * K + k0 + csw * 4,
            &lds_[i * 2048 + tid * 8]);
    }
#pragma unroll
    for (int i = 0; i < 4; ++i)                 // B: bf16, 16 KB
      GLOAD(Bb + (long)(i * 32 + stB_r) * K + k0 + stB_ks * 8,
            &lds_[16384 + i * 2048 + tid * 8]);
    WAITVM0();
    __syncthreads();

    bf16x8 a[4][2], b[4][2];
#pragma unroll
    for (int m = 0; m < 4; ++m)
#pragma unroll
      for (int kk = 0; kk < 2; ++kk) {
        const int r = wr * 64 + m * 16 + lr;
        const int s8 = kk * 4 + q;
        const int c0 = (2 * s8) ^ (r & 15);
        const int c1 = (2 * s8 + 1) ^ (r & 15);
        f32x4 lo = *(const f32x4*)&lds_[r * 128 + c0 * 8];
        f32x4 hi = *(const f32x4*)&lds_[r * 128 + c1 * 8];
        bf16x8 o;
#pragma unroll
        for (int j = 0; j < 4; ++j) {
          o[j]     = (__bf16)lo[j];
          o[j + 4] = (__bf16)hi[j];
        }
        a[m][kk] = o;
      }
#pragma unroll
    for (int n = 0; n < 4; ++n)
#pragma unroll
      for (int kk = 0; kk < 2; ++kk) {
        const int c = wc * 64 + n * 16 + lr, s = kk * 4 + q;
        b[n][kk] = *(const bf16x8*)&lds_[16384 + c * 64 + ((s ^ (c & 7)) * 8)];
      }
#pragma unroll
    for (int kk = 0; kk < 2; ++kk)
#pragma unroll
      for (int n = 0; n < 4; ++n)
#pragma unroll
        for (int m = 0; m < 4; ++m)
          acc[m][n] = __builtin_amdgcn_mfma_f32_16x16x32_bf16(
              a[m][kk], b[n][kk], acc[m][n], 0, 0, 0);
    __syncthreads();
  }

  // epilogue. C/D layout: col = l&15, row = (l>>4)*4 + reg  [m89]
  const int r4 = q * 4;
  const float* bp = (bz == 0) ? bias0 : ((bz == 1) ? bias1 : bias2);

  if (bz == 2) {
    // V projection: write V^T directly (batch-major: b*DH*S + col*S + s).
    // Per-wave 64x64 transpose through the dead LDS (region w*4352 u16,
    // rows padded to 68 u16 so writes spread across banks).
    const long bb = arow0 >> 11;               // batch (block-uniform)
    const long s0 = arow0 & 2047;              // seq base within batch
    u16* lt = &lds_[w * 4352];
#pragma unroll
    for (int mf = 0; mf < 4; ++mf)
#pragma unroll
      for (int nf = 0; nf < 4; ++nf)
#pragma unroll
        for (int r = 0; r < 4; ++r) {
          const long col = bcol0 + wc * 64 + nf * 16 + lr;
          const int c_loc = nf * 16 + lr;
          const int r_loc = mf * 16 + r4 + r;
          lt[c_loc * 68 + r_loc] = f2bf(acc[mf][nf][r] + bp[col]);
        }
    __syncthreads();   // LDS writes visible before cross-lane reads
#pragma unroll
    for (int jj = 0; jj < 8; ++jj) {
      const int c = (l >> 3) + 8 * jj;          // 0..63
      const int r0i = (l & 7) * 8;              // 0..56, 8-aligned
      u16x8 vv;
#pragma unroll
      for (int e = 0; e < 8; ++e) vv[e] = lt[c * 68 + r0i + e];
      const long col = bcol0 + wc * 64 + c;
      const long srow = s0 + wr * 64 + r0i;
      *(u16x8*)&VT[bb * (long)DH * S_ + col * S_ + srow] = vv;  // 16B store
    }
  } else {
#pragma unroll
    for (int mf = 0; mf < 4; ++mf)
#pragma unroll
      for (int nf = 0; nf < 4; ++nf)
#pragma unroll
        for (int r = 0; r < 4; ++r) {
          const long row = arow0 + wr * 64 + mf * 16 + r4 + r;
          const long col = bcol0 + wc * 64 + nf * 16 + lr;
          float v = acc[mf][nf][r] + bp[col];
          C[bz * sC + row * N + col] = f2bf(v);
        }
  }
}

// ---------------------------------------------------------------------------
// gemm97: m97-replica bf16 B^T GEMM (proven 937 TF).  32 KB LDS, (256,4).
// ---------------------------------------------------------------------------
#define EPI_BF16_ROWSCALE 1   // C u16 : v / rowsum  (rowsum from Psum[.,16])
#define EPI_F32_BIAS      2   // C f32 : v + bias0[col]

template <int EPI>
__global__ __launch_bounds__(256, 4)
void gemm97(const u16* __restrict__ A, const u16* __restrict__ Bm,
            void* __restrict__ C,
            const float* __restrict__ bias0,
            const float* __restrict__ Psum,
            int M, int N, int K,
            long sA, long sB, long sC,
            int nbx, int nby) {
  __shared__ u16 lds_[16384];   // A 8192 u16 | B 8192 u16
  __shared__ float invs_s[(EPI == EPI_BF16_ROWSCALE) ? 128 : 1];

  const int tid = threadIdx.x;
  const int w = tid >> 6, l = tid & 63;
  const int wr = w >> 1, wc = w & 1;
  const int lr = l & 15, q = l >> 4;

  // T1 bijective XCD-chunk swizzle (grid % 8 == 0)
  const int flat = blockIdx.x;
  const int swz = (flat & 7) * ((int)gridDim.x >> 3) + (flat >> 3);
  const int bx = swz % nbx;
  const int rest = swz / nbx;
  const int by = rest % nby;
  const int bz = rest / nby;

  const long arow0 = (long)by * 128;
  const long bcol0 = (long)bx * 128;
  const u16* Ab = A + bz * sA + arow0 * K;
  const u16* Bb = Bm + bz * sB + bcol0 * K;
  const int nt = K >> 6;

  if constexpr (EPI == EPI_BF16_ROWSCALE) {
    if (tid < 128) {
      const float4* p = (const float4*)(Psum + ((long)bz * S_ + arow0 + tid) * 16);
      float4 a = p[0], b = p[1], c = p[2], d = p[3];
      float s = (a.x + a.y + a.z + a.w) + (b.x + b.y + b.z + b.w)
              + (c.x + c.y + c.z + c.w) + (d.x + d.y + d.z + d.w);
      invs_s[tid] = 1.0f / s;
    }
  }

  const int st_r = tid >> 3;
  const int st_ks = (tid & 7) ^ (st_r & 7);

  floatx4 acc[4][4] = {};

  for (int t = 0; t < nt; ++t) {
    const long k0 = (long)t << 6;
#pragma unroll
    for (int i = 0; i < 4; ++i)
      GLOAD(Ab + (long)(i * 32 + st_r) * K + k0 + st_ks * 8,
            &lds_[i * 2048 + tid * 8]);
#pragma unroll
    for (int i = 0; i < 4; ++i)
      GLOAD(Bb + (long)(i * 32 + st_r) * K + k0 + st_ks * 8,
            &lds_[8192 + i * 2048 + tid * 8]);
    WAITVM0();
    __syncthreads();

    bf16x8 a[4][2], b[4][2];
#pragma unroll
    for (int m = 0; m < 4; ++m)
#pragma unroll
      for (int kk = 0; kk < 2; ++kk) {
        const int r = wr * 64 + m * 16 + lr, s = kk * 4 + q;
        a[m][kk] = *(const bf16x8*)&lds_[r * 64 + ((s ^ (r & 7)) * 8)];
      }
#pragma unroll
    for (int n = 0; n < 4; ++n)
#pragma unroll
      for (int kk = 0; kk < 2; ++kk) {
        const int c = wc * 64 + n * 16 + lr, s = kk * 4 + q;
        b[n][kk] = *(const bf16x8*)&lds_[8192 + c * 64 + ((s ^ (c & 7)) * 8)];
      }
#pragma unroll
    for (int kk = 0; kk < 2; ++kk)
#pragma unroll
      for (int n = 0; n < 4; ++n)
#pragma unroll
        for (int m = 0; m < 4; ++m)
          acc[m][n] = __builtin_amdgcn_mfma_f32_16x16x32_bf16(
              a[m][kk], b[n][kk], acc[m][n], 0, 0, 0);
    __syncthreads();
  }

  const int r4 = q * 4;
#pragma unroll
  for (int mf = 0; mf < 4; ++mf)
#pragma unroll
    for (int nf = 0; nf < 4; ++nf)
#pragma unroll
      for (int r = 0; r < 4; ++r) {
        const long row = arow0 + wr * 64 + mf * 16 + r4 + r;
        const long col = bcol0 + wc * 64 + nf * 16 + lr;
        float v = acc[mf][nf][r];
        if constexpr (EPI == EPI_BF16_ROWSCALE) {
          v *= invs_s[wr * 64 + mf * 16 + r4 + r];
          ((u16*)C)[bz * sC + row * N + col] = f2bf(v);
        } else {  // EPI_F32_BIAS
          v += bias0[col];
          ((float*)C)[bz * sC + row * N + col] = v;
        }
      }
}

// ---------------------------------------------------------------------------
// pexp128: m97-structure GEMM (K=1024, nt=16) computing
//   P = exp((Q @ K^T)/32) masked->0 (bf16) + per-block row partial sums.
// Pure-GEMM K-loop; mask bits from the 2MB packed bitmask (R12/R15/R18-
// verified interleaved layout + indexing), coop-loaded (2KB) into dead LDS.
// ---------------------------------------------------------------------------
__global__ __launch_bounds__(256, 4)
void pexp128(const u16* __restrict__ Q, const u16* __restrict__ Kb_,
             u16* __restrict__ P, const u32* __restrict__ packed,
             float* __restrict__ Psum) {
  __shared__ u16 lds_[16384];

  const int tid = threadIdx.x;
  const int w = tid >> 6, l = tid & 63;
  const int wr = w >> 1, wc = w & 1;
  const int lr = l & 15, q = l >> 4;

  // T1 swizzle; grid 1024 = nbx16 x nby16 x z4
  const int flat = blockIdx.x;
  const int swz = (flat & 7) * ((int)gridDim.x >> 3) + (flat >> 3);
  const int bx = swz & 15;
  const int rest = swz >> 4;
  const int by = rest & 15;
  const int bz = rest >> 4;

  const long arow0 = (long)by * 128;
  const long bcol0 = (long)bx * 128;
  const int K = DH;
  const u16* Ab = Q + (long)bz * S_ * DH + arow0 * K;
  const u16* Bb = Kb_ + (long)bz * S_ * DH + bcol0 * K;

  const int st_r = tid >> 3;
  const int st_ks = (tid & 7) ^ (st_r & 7);

  floatx4 acc[4][4] = {};

#pragma unroll 4
  for (int t = 0; t < 16; ++t) {
    const long k0 = (long)t << 6;
#pragma unroll
    for (int i = 0; i < 4; ++i)
      GLOAD(Ab + (long)(i * 32 + st_r) * K + k0 + st_ks * 8,
            &lds_[i * 2048 + tid * 8]);
#pragma unroll
    for (int i = 0; i < 4; ++i)
      GLOAD(Bb + (long)(i * 32 + st_r) * K + k0 + st_ks * 8,
            &lds_[8192 + i * 2048 + tid * 8]);
    WAITVM0();
    __syncthreads();

    bf16x8 a[4][2], b[4][2];
#pragma unroll
    for (int m = 0; m < 4; ++m)
#pragma unroll
      for (int kk = 0; kk < 2; ++kk) {
        const int r = wr * 64 + m * 16 + lr, s = kk * 4 + q;
        a[m][kk] = *(const bf16x8*)&lds_[r * 64 + ((s ^ (r & 7)) * 8)];
      }
#pragma unroll
    for (int n = 0; n < 4; ++n)
#pragma unroll
      for (int kk = 0; kk < 2; ++kk) {
        const int c = wc * 64 + n * 16 + lr, s = kk * 4 + q;
        b[n][kk] = *(const bf16x8*)&lds_[8192 + c * 64 + ((s ^ (c & 7)) * 8)];
      }
#pragma unroll
    for (int kk = 0; kk < 2; ++kk)
#pragma unroll
      for (int n = 0; n < 4; ++n)
#pragma unroll
        for (int m = 0; m < 4; ++m)
          acc[m][n] = __builtin_amdgcn_mfma_f32_16x16x32_bf16(
              a[m][kk], b[n][kk], acc[m][n], 0, 0, 0);
    __syncthreads();
  }

  // ---- epilogue.
  // 1) coop-load packed-mask u32 halves (R12/R15/R18-verified): for row
  //    arow0+lrow, j=0..3: pw[lrow*4+j] = packed32[g*8 + j*2 + (bx&1)],
  //    g = bz*16384 + row*8 + (bx>>1).  2KB into dead LDS.
  u32* pw = (u32*)&lds_[8192];    // 512 u32
  {
    const int half = bx & 1;
    const int lrow = tid >> 1;                 // 0..127
    const int j0 = (tid & 1) * 2;              // 0 or 2
    const long g = (long)bz * 16384 + (arow0 + lrow) * 8 + (bx >> 1);
    pw[lrow * 4 + j0]     = packed[g * 8 + j0 * 2 + half];
    pw[lrow * 4 + j0 + 1] = packed[g * 8 + (j0 + 1) * 2 + half];
  }
  __syncthreads();

  // 2) p = bit ? exp(v/32) : 0; bf16 store; row partial sums.
  //    word = pw[lrow*4 + (lr&3)], bit = wc*16 + nf*4 + (lr>>2)  [R12/R15]
  const int r4 = q * 4;
  float rsum[4][4];
#pragma unroll
  for (int mf = 0; mf < 4; ++mf)
#pragma unroll
    for (int r = 0; r < 4; ++r) rsum[mf][r] = 0.f;

#pragma unroll
  for (int mf = 0; mf < 4; ++mf)
#pragma unroll
    for (int r = 0; r < 4; ++r) {
      const int lrow = wr * 64 + mf * 16 + r4 + r;
      const long row = arow0 + lrow;
      const u32 word = pw[lrow * 4 + (lr & 3)];
#pragma unroll
      for (int nf = 0; nf < 4; ++nf) {
        const int bitpos = wc * 16 + nf * 4 + (lr >> 2);
        const long col = bcol0 + wc * 64 + nf * 16 + lr;
        float p = 0.f;
        if ((word >> bitpos) & 1u) p = __expf(acc[mf][nf][r] * 0.03125f);
        P[(long)bz * S_ * S_ + row * S_ + col] = f2bf(p);
        rsum[mf][r] += p;
      }
    }
  __syncthreads();   // all bit-reads done before Psum scratch reuses LDS

  // 3) reduce over the 16 lr-lanes, then across the 2 wc waves via LDS
  float* sc = (float*)lds_;
#pragma unroll
  for (int mf = 0; mf < 4; ++mf)
#pragma unroll
    for (int r = 0; r < 4; ++r) {
      float s = rsum[mf][r];
      s += __shfl_xor(s, 1); s += __shfl_xor(s, 2);
      s += __shfl_xor(s, 4); s += __shfl_xor(s, 8);
      if (lr == 0) sc[(wr * 64 + mf * 16 + r4 + r) * 2 + wc] = s;
    }
  __syncthreads();
  if (tid < 128) {
    float tot = sc[tid * 2] + sc[tid * 2 + 1];
    Psum[((long)bz * S_ + arow0 + tid) * 16 + bx] = tot;
  }
}

// ---------------------------------------------------------------------------
extern "C" void kernel_launch(void* const* d_in, const int* in_sizes, int n_in,
                              void* d_out, int out_size, void* d_ws, size_t ws_size,
                              hipStream_t stream) {
  const float* q    = (const float*)d_in[0];
  const float* k    = (const float*)d_in[1];
  const float* v    = (const float*)d_in[2];
  const int*   mask = (const int*)d_in[3];
  const float* Wq   = (const float*)d_in[4];
  const float* bq   = (const float*)d_in[5];
  const float* Wk   = (const float*)d_in[6];
  const float* bk   = (const float*)d_in[7];
  const float* Wv   = (const float*)d_in[8];
  const float* bv   = (const float*)d_in[9];
  const float* Wo   = (const float*)d_in[10];
  const float* bo   = (const float*)d_in[11];

  const long BS = (long)B_ * S_;      // 8192
  const long nQ = BS * DH;            // 8,388,608
  const long nW = (long)DH * DIN;     // 1,048,576
  const long nE = (long)B_ * S_ * S_; // 16,777,216

  char* ws = (char*)d_ws;
  size_t off = 0;
  auto alloc = [&](size_t bytes) {
    void* p = ws + off; off += (bytes + 255) & ~(size_t)255; return p;
  };

  u16* wqb  = (u16*)alloc(4 * nW * 2);       // wq|wk|wv|wo contiguous
  u16* Qb   = (u16*)alloc(nQ * 2);           // Qb,Kbf contiguous (z-batch)
  u16* Kbf  = (u16*)alloc(nQ * 2);
  u16* VT   = (u16*)alloc(nQ * 2);           // V^T written by proj directly
  u16* P    = (u16*)alloc(nE * 2);           // exp(e) unnormalized, bf16
  u64* pk   = (u64*)alloc(nE / 8);           // packed mask bits (2MB)
  float* Psum = (float*)alloc(BS * 16 * 4);  // per-block row partials
  u16* Yb   = (u16*)alloc(nQ * 2);           // attention output
  u16* wob  = wqb + 3 * nW;

  // 1. weight cast + mask pack (q/k/v consumed in fp32 by proj staging)
  wcast<<<dim3(4096), 256, 0, stream>>>(Wq, Wk, Wv, Wo, wqb);
  mask_pack<<<dim3(16384), 256, 0, stream>>>(mask, pk);

  // 2. QKV projections, z=3, A staged from fp32; bz==2 writes V^T directly:
  //    grid 8x64x3 = 1536
  gemm97f<<<dim3(1536), 256, 0, stream>>>(q, k, v, wqb, Qb, VT, bq, bk, bv,
      (int)BS, DH, DIN, nW, nQ, 8, 64);

  // 3. P = exp((Q K^T)/32) masked->0 + row partials: grid 16x16x4 = 1024
  pexp128<<<dim3(1024), 256, 0, stream>>>(Qb, Kbf, P, (const u32*)pk, Psum);

  // 4. Y = (P @ V) / rowsum == P[S,S] @ VT[DH,S]^T: grid 8x16x4 = 512
  gemm97<EPI_BF16_ROWSCALE><<<dim3(512), 256, 0, stream>>>(P, VT, Yb,
      nullptr, Psum, S_, DH, S_,
      (long)S_ * S_, (long)DH * S_, (long)S_ * DH, 8, 16);

  // 5. out = Y @ Wo^T + bo -> fp32 d_out: grid 8x64 = 512
  gemm97<EPI_F32_BIAS><<<dim3(512), 256, 0, stream>>>(Yb, wob, d_out,
      bo, nullptr, (int)BS, DOUT, DH, 0, 0, 0, 8, 64);
}

// Round 21
// 198.690 us; speedup vs baseline: 1.2138x; 1.0111x over previous
//
#include <hip/hip_runtime.h>
#include <hip/hip_bf16.h>

// Problem constants (from reference)
#define B_   4
#define S_   2048
#define DIN  1024
#define DH   1024
#define DOUT 1024

typedef __attribute__((ext_vector_type(8))) __bf16 bf16x8;
typedef __attribute__((ext_vector_type(4))) float floatx4;
typedef __attribute__((ext_vector_type(4))) float f32x4;   // native vec for nontemporal
typedef __attribute__((ext_vector_type(4))) int i32x4;
typedef __attribute__((ext_vector_type(4))) u_short u16x4;
typedef __attribute__((ext_vector_type(8))) u_short u16x8;
typedef unsigned short u16;
typedef unsigned int u32;
typedef unsigned long long u64;

__device__ inline u16 f2bf(float f) {
  union { float f; u32 u; } x; x.f = f;
  u32 r = x.u + 0x7fffu + ((x.u >> 16) & 1u);  // RTNE
  return (u16)(r >> 16);
}

#define GLOAD(SRC, DST) __builtin_amdgcn_global_load_lds(                     \
    (const __attribute__((address_space(1))) u32*)(SRC),                      \
    (__attribute__((address_space(3))) u32*)(DST), 16, 0, 0)
#define WAITVM0() asm volatile("s_waitcnt vmcnt(0)" ::: "memory")

// ---------------------------------------------------------------------------
// prep: merged wcast + mask_pack (both regions small & homogeneous -- unlike
// R10-12's failed merges of huge imbalanced regions).  One launch:
//   [0,4096):      fp32 -> bf16 weight cast (1024 blocks per weight)
//   [4096,20480):  mask int32 -> 2MB bitmask, int4 + 4x __ballot
//                  (R12/R15/R18-verified interleaved layout:
//                   packed[g*4+j] bit l <-> mask[g*256 + 4l + j])
// ---------------------------------------------------------------------------
__global__ __launch_bounds__(256)
void prep(const float* __restrict__ w0, const float* __restrict__ w1,
          const float* __restrict__ w2, const float* __restrict__ w3,
          u16* __restrict__ dst,
          const int* __restrict__ mask, u64* __restrict__ packed) {
  const long nW = (long)DH * DIN;          // 1,048,576
  const long b = blockIdx.x;
  if (b < 4096) {
    const int r = (int)(b >> 10);          // 1024 blocks per weight
    const float* src = (r == 0) ? w0 : (r == 1) ? w1 : (r == 2) ? w2 : w3;
    long i = (b & 1023) * 256 + threadIdx.x;
    f32x4 vv = __builtin_nontemporal_load(((const f32x4*)src) + i);
    u16x4 o;
    o.x = f2bf(vv.x); o.y = f2bf(vv.y); o.z = f2bf(vv.z); o.w = f2bf(vv.w);
    ((u16x4*)(dst + (long)r * nW))[i] = o;
  } else {
    const long f = (b - 4096) * 256 + threadIdx.x;   // int4 index
    i32x4 m4 = __builtin_nontemporal_load(((const i32x4*)mask) + f);
    u64 b0 = __ballot(m4.x != 0);
    u64 b1 = __ballot(m4.y != 0);
    u64 b2 = __ballot(m4.z != 0);
    u64 b3 = __ballot(m4.w != 0);
    if ((threadIdx.x & 63) == 0) {
      const long g = f >> 6;               // wave-uniform (f base 64-aligned)
      ulonglong2 p01; p01.x = b0; p01.y = b1;
      ulonglong2 p23; p23.x = b2; p23.y = b3;
      ((ulonglong2*)(packed + g * 4))[0] = p01;
      ((ulonglong2*)(packed + g * 4))[1] = p23;
    }
  }
}

// ---------------------------------------------------------------------------
// gemm97f: m97-structure GEMM with A staged DIRECTLY FROM FP32 via
// global_load_lds (R17-proven net win).  A fp32 32 KB + B bf16 16 KB LDS,
// launch_bounds(256,3).  For bz==2 (V projection) the epilogue writes V^T
// directly (R20-proven): per-wave 64x64 transpose through the dead LDS
// (pad-68 rows), batch-major stores b*DH*S + col*S + s.
// ---------------------------------------------------------------------------
__global__ __launch_bounds__(256, 3)
void gemm97f(const float* __restrict__ Af0, const float* __restrict__ Af1,
             const float* __restrict__ Af2,
             const u16* __restrict__ Bm, u16* __restrict__ C,
             u16* __restrict__ VT,
             const float* __restrict__ bias0, const float* __restrict__ bias1,
             const float* __restrict__ bias2,
             int M, int N, int K, long sB, long sC,
             int nbx, int nby) {
  __shared__ u16 lds_[24576];   // A fp32 [0,16384) u16 | B bf16 [16384,24576)

  const int tid = threadIdx.x;
  const int w = tid >> 6, l = tid & 63;
  const int wr = w >> 1, wc = w & 1;
  const int lr = l & 15, q = l >> 4;

  // T1 bijective XCD-chunk swizzle (grid % 8 == 0)
  const int flat = blockIdx.x;
  const int swz = (flat & 7) * ((int)gridDim.x >> 3) + (flat >> 3);
  const int bx = swz % nbx;
  const int rest = swz / nbx;
  const int by = rest % nby;
  const int bz = rest / nby;

  const long arow0 = (long)by * 128;
  const long bcol0 = (long)bx * 128;
  const float* As = (bz == 0) ? Af0 : ((bz == 1) ? Af1 : Af2);
  const float* Afp = As + arow0 * K;
  const u16* Bb = Bm + bz * sB + bcol0 * K;
  const int nt = K >> 6;

  const int stA_r = tid >> 4;                   // 0..15 row in 16-row group
  const int stA_c = tid & 15;                   // 16B chunk id (4 f32)
  const int stB_r = tid >> 3;
  const int stB_ks = (tid & 7) ^ (stB_r & 7);

  floatx4 acc[4][4] = {};

  for (int t = 0; t < nt; ++t) {
    const long k0 = (long)t << 6;               // elements (f32 or bf16)
#pragma unroll
    for (int i = 0; i < 8; ++i) {               // A: fp32, 32 KB
      const int row = i * 16 + stA_r;
      const int csw = stA_c ^ (row & 15);
      GLOAD(Afp + (long)row * K + k0 + csw * 4,
            &lds_[i * 2048 + tid * 8]);
    }
#pragma unroll
    for (int i = 0; i < 4; ++i)                 // B: bf16, 16 KB
      GLOAD(Bb + (long)(i * 32 + stB_r) * K + k0 + stB_ks * 8,
            &lds_[16384 + i * 2048 + tid * 8]);
    WAITVM0();
    __syncthreads();

    bf16x8 a[4][2], b[4][2];
#pragma unroll
    for (int m = 0; m < 4; ++m)
#pragma unroll
      for (int kk = 0; kk < 2; ++kk) {
        const int r = wr * 64 + m * 16 + lr;
        const int s8 = kk * 4 + q;
        const int c0 = (2 * s8) ^ (r & 15);
        const int c1 = (2 * s8 + 1) ^ (r & 15);
        f32x4 lo = *(const f32x4*)&lds_[r * 128 + c0 * 8];
        f32x4 hi = *(const f32x4*)&lds_[r * 128 + c1 * 8];
        bf16x8 o;
#pragma unroll
        for (int j = 0; j < 4; ++j) {
          o[j]     = (__bf16)lo[j];
          o[j + 4] = (__bf16)hi[j];
        }
        a[m][kk] = o;
      }
#pragma unroll
    for (int n = 0; n < 4; ++n)
#pragma unroll
      for (int kk = 0; kk < 2; ++kk) {
        const int c = wc * 64 + n * 16 + lr, s = kk * 4 + q;
        b[n][kk] = *(const bf16x8*)&lds_[16384 + c * 64 + ((s ^ (c & 7)) * 8)];
      }
#pragma unroll
    for (int kk = 0; kk < 2; ++kk)
#pragma unroll
      for (int n = 0; n < 4; ++n)
#pragma unroll
        for (int m = 0; m < 4; ++m)
          acc[m][n] = __builtin_amdgcn_mfma_f32_16x16x32_bf16(
              a[m][kk], b[n][kk], acc[m][n], 0, 0, 0);
    __syncthreads();
  }

  // epilogue. C/D layout: col = l&15, row = (l>>4)*4 + reg  [m89]
  const int r4 = q * 4;
  const float* bp = (bz == 0) ? bias0 : ((bz == 1) ? bias1 : bias2);

  if (bz == 2) {
    // V projection: write V^T directly (batch-major: b*DH*S + col*S + s).
    const long bb = arow0 >> 11;               // batch (block-uniform)
    const long s0 = arow0 & 2047;              // seq base within batch
    u16* lt = &lds_[w * 4352];
#pragma unroll
    for (int mf = 0; mf < 4; ++mf)
#pragma unroll
      for (int nf = 0; nf < 4; ++nf)
#pragma unroll
        for (int r = 0; r < 4; ++r) {
          const long col = bcol0 + wc * 64 + nf * 16 + lr;
          const int c_loc = nf * 16 + lr;
          const int r_loc = mf * 16 + r4 + r;
          lt[c_loc * 68 + r_loc] = f2bf(acc[mf][nf][r] + bp[col]);
        }
    __syncthreads();   // LDS writes visible before cross-lane reads
#pragma unroll
    for (int jj = 0; jj < 8; ++jj) {
      const int c = (l >> 3) + 8 * jj;          // 0..63
      const int r0i = (l & 7) * 8;              // 0..56, 8-aligned
      u16x8 vv;
#pragma unroll
      for (int e = 0; e < 8; ++e) vv[e] = lt[c * 68 + r0i + e];
      const long col = bcol0 + wc * 64 + c;
      const long srow = s0 + wr * 64 + r0i;
      *(u16x8*)&VT[bb * (long)DH * S_ + col * S_ + srow] = vv;  // 16B store
    }
  } else {
#pragma unroll
    for (int mf = 0; mf < 4; ++mf)
#pragma unroll
      for (int nf = 0; nf < 4; ++nf)
#pragma unroll
        for (int r = 0; r < 4; ++r) {
          const long row = arow0 + wr * 64 + mf * 16 + r4 + r;
          const long col = bcol0 + wc * 64 + nf * 16 + lr;
          float v = acc[mf][nf][r] + bp[col];
          C[bz * sC + row * N + col] = f2bf(v);
        }
  }
}

// ---------------------------------------------------------------------------
// gemm97: m97-replica bf16 B^T GEMM (proven 937 TF).  32 KB LDS, (256,4).
// ---------------------------------------------------------------------------
#define EPI_BF16_ROWSCALE 1   // C u16 : v / rowsum  (rowsum from Psum[.,16])
#define EPI_F32_BIAS      2   // C f32 : v + bias0[col]

template <int EPI>
__global__ __launch_bounds__(256, 4)
void gemm97(const u16* __restrict__ A, const u16* __restrict__ Bm,
            void* __restrict__ C,
            const float* __restrict__ bias0,
            const float* __restrict__ Psum,
            int M, int N, int K,
            long sA, long sB, long sC,
            int nbx, int nby) {
  __shared__ u16 lds_[16384];   // A 8192 u16 | B 8192 u16
  __shared__ float invs_s[(EPI == EPI_BF16_ROWSCALE) ? 128 : 1];

  const int tid = threadIdx.x;
  const int w = tid >> 6, l = tid & 63;
  const int wr = w >> 1, wc = w & 1;
  const int lr = l & 15, q = l >> 4;

  // T1 bijective XCD-chunk swizzle (grid % 8 == 0)
  const int flat = blockIdx.x;
  const int swz = (flat & 7) * ((int)gridDim.x >> 3) + (flat >> 3);
  const int bx = swz % nbx;
  const int rest = swz / nbx;
  const int by = rest % nby;
  const int bz = rest / nby;

  const long arow0 = (long)by * 128;
  const long bcol0 = (long)bx * 128;
  const u16* Ab = A + bz * sA + arow0 * K;
  const u16* Bb = Bm + bz * sB + bcol0 * K;
  const int nt = K >> 6;

  if constexpr (EPI == EPI_BF16_ROWSCALE) {
    if (tid < 128) {
      const float4* p = (const float4*)(Psum + ((long)bz * S_ + arow0 + tid) * 16);
      float4 a = p[0], b = p[1], c = p[2], d = p[3];
      float s = (a.x + a.y + a.z + a.w) + (b.x + b.y + b.z + b.w)
              + (c.x + c.y + c.z + c.w) + (d.x + d.y + d.z + d.w);
      invs_s[tid] = 1.0f / s;
    }
  }

  const int st_r = tid >> 3;
  const int st_ks = (tid & 7) ^ (st_r & 7);

  floatx4 acc[4][4] = {};

  for (int t = 0; t < nt; ++t) {
    const long k0 = (long)t << 6;
#pragma unroll
    for (int i = 0; i < 4; ++i)
      GLOAD(Ab + (long)(i * 32 + st_r) * K + k0 + st_ks * 8,
            &lds_[i * 2048 + tid * 8]);
#pragma unroll
    for (int i = 0; i < 4; ++i)
      GLOAD(Bb + (long)(i * 32 + st_r) * K + k0 + st_ks * 8,
            &lds_[8192 + i * 2048 + tid * 8]);
    WAITVM0();
    __syncthreads();

    bf16x8 a[4][2], b[4][2];
#pragma unroll
    for (int m = 0; m < 4; ++m)
#pragma unroll
      for (int kk = 0; kk < 2; ++kk) {
        const int r = wr * 64 + m * 16 + lr, s = kk * 4 + q;
        a[m][kk] = *(const bf16x8*)&lds_[r * 64 + ((s ^ (r & 7)) * 8)];
      }
#pragma unroll
    for (int n = 0; n < 4; ++n)
#pragma unroll
      for (int kk = 0; kk < 2; ++kk) {
        const int c = wc * 64 + n * 16 + lr, s = kk * 4 + q;
        b[n][kk] = *(const bf16x8*)&lds_[8192 + c * 64 + ((s ^ (c & 7)) * 8)];
      }
#pragma unroll
    for (int kk = 0; kk < 2; ++kk)
#pragma unroll
      for (int n = 0; n < 4; ++n)
#pragma unroll
        for (int m = 0; m < 4; ++m)
          acc[m][n] = __builtin_amdgcn_mfma_f32_16x16x32_bf16(
              a[m][kk], b[n][kk], acc[m][n], 0, 0, 0);
    __syncthreads();
  }

  const int r4 = q * 4;
#pragma unroll
  for (int mf = 0; mf < 4; ++mf)
#pragma unroll
    for (int nf = 0; nf < 4; ++nf)
#pragma unroll
      for (int r = 0; r < 4; ++r) {
        const long row = arow0 + wr * 64 + mf * 16 + r4 + r;
        const long col = bcol0 + wc * 64 + nf * 16 + lr;
        float v = acc[mf][nf][r];
        if constexpr (EPI == EPI_BF16_ROWSCALE) {
          v *= invs_s[wr * 64 + mf * 16 + r4 + r];
          ((u16*)C)[bz * sC + row * N + col] = f2bf(v);
        } else {  // EPI_F32_BIAS
          v += bias0[col];
          ((float*)C)[bz * sC + row * N + col] = v;
        }
      }
}

// ---------------------------------------------------------------------------
// pexp128: m97-structure GEMM (K=1024, nt=16) computing
//   P = exp((Q @ K^T)/32) masked->0 (bf16) + per-block row partial sums.
// Pure-GEMM K-loop; mask bits from the 2MB packed bitmask (R12/R15/R18-
// verified interleaved layout + indexing), coop-loaded (2KB) into dead LDS.
// ---------------------------------------------------------------------------
__global__ __launch_bounds__(256, 4)
void pexp128(const u16* __restrict__ Q, const u16* __restrict__ Kb_,
             u16* __restrict__ P, const u32* __restrict__ packed,
             float* __restrict__ Psum) {
  __shared__ u16 lds_[16384];

  const int tid = threadIdx.x;
  const int w = tid >> 6, l = tid & 63;
  const int wr = w >> 1, wc = w & 1;
  const int lr = l & 15, q = l >> 4;

  // T1 swizzle; grid 1024 = nbx16 x nby16 x z4
  const int flat = blockIdx.x;
  const int swz = (flat & 7) * ((int)gridDim.x >> 3) + (flat >> 3);
  const int bx = swz & 15;
  const int rest = swz >> 4;
  const int by = rest & 15;
  const int bz = rest >> 4;

  const long arow0 = (long)by * 128;
  const long bcol0 = (long)bx * 128;
  const int K = DH;
  const u16* Ab = Q + (long)bz * S_ * DH + arow0 * K;
  const u16* Bb = Kb_ + (long)bz * S_ * DH + bcol0 * K;

  const int st_r = tid >> 3;
  const int st_ks = (tid & 7) ^ (st_r & 7);

  floatx4 acc[4][4] = {};

#pragma unroll 4
  for (int t = 0; t < 16; ++t) {
    const long k0 = (long)t << 6;
#pragma unroll
    for (int i = 0; i < 4; ++i)
      GLOAD(Ab + (long)(i * 32 + st_r) * K + k0 + st_ks * 8,
            &lds_[i * 2048 + tid * 8]);
#pragma unroll
    for (int i = 0; i < 4; ++i)
      GLOAD(Bb + (long)(i * 32 + st_r) * K + k0 + st_ks * 8,
            &lds_[8192 + i * 2048 + tid * 8]);
    WAITVM0();
    __syncthreads();

    bf16x8 a[4][2], b[4][2];
#pragma unroll
    for (int m = 0; m < 4; ++m)
#pragma unroll
      for (int kk = 0; kk < 2; ++kk) {
        const int r = wr * 64 + m * 16 + lr, s = kk * 4 + q;
        a[m][kk] = *(const bf16x8*)&lds_[r * 64 + ((s ^ (r & 7)) * 8)];
      }
#pragma unroll
    for (int n = 0; n < 4; ++n)
#pragma unroll
      for (int kk = 0; kk < 2; ++kk) {
        const int c = wc * 64 + n * 16 + lr, s = kk * 4 + q;
        b[n][kk] = *(const bf16x8*)&lds_[8192 + c * 64 + ((s ^ (c & 7)) * 8)];
      }
#pragma unroll
    for (int kk = 0; kk < 2; ++kk)
#pragma unroll
      for (int n = 0; n < 4; ++n)
#pragma unroll
        for (int m = 0; m < 4; ++m)
          acc[m][n] = __builtin_amdgcn_mfma_f32_16x16x32_bf16(
              a[m][kk], b[n][kk], acc[m][n], 0, 0, 0);
    __syncthreads();
  }

  // ---- epilogue.
  // 1) coop-load packed-mask u32 halves (R12/R15/R18-verified): for row
  //    arow0+lrow, j=0..3: pw[lrow*4+j] = packed32[g*8 + j*2 + (bx&1)],
  //    g = bz*16384 + row*8 + (bx>>1).  2KB into dead LDS.
  u32* pw = (u32*)&lds_[8192];    // 512 u32
  {
    const int half = bx & 1;
    const int lrow = tid >> 1;                 // 0..127
    const int j0 = (tid & 1) * 2;              // 0 or 2
    const long g = (long)bz * 16384 + (arow0 + lrow) * 8 + (bx >> 1);
    pw[lrow * 4 + j0]     = packed[g * 8 + j0 * 2 + half];
    pw[lrow * 4 + j0 + 1] = packed[g * 8 + (j0 + 1) * 2 + half];
  }
  __syncthreads();

  // 2) p = bit ? exp(v/32) : 0; bf16 store; row partial sums.
  //    word = pw[lrow*4 + (lr&3)], bit = wc*16 + nf*4 + (lr>>2)  [R12/R15]
  const int r4 = q * 4;
  float rsum[4][4];
#pragma unroll
  for (int mf = 0; mf < 4; ++mf)
#pragma unroll
    for (int r = 0; r < 4; ++r) rsum[mf][r] = 0.f;

#pragma unroll
  for (int mf = 0; mf < 4; ++mf)
#pragma unroll
    for (int r = 0; r < 4; ++r) {
      const int lrow = wr * 64 + mf * 16 + r4 + r;
      const long row = arow0 + lrow;
      const u32 word = pw[lrow * 4 + (lr & 3)];
#pragma unroll
      for (int nf = 0; nf < 4; ++nf) {
        const int bitpos = wc * 16 + nf * 4 + (lr >> 2);
        const long col = bcol0 + wc * 64 + nf * 16 + lr;
        float p = 0.f;
        if ((word >> bitpos) & 1u) p = __expf(acc[mf][nf][r] * 0.03125f);
        P[(long)bz * S_ * S_ + row * S_ + col] = f2bf(p);
        rsum[mf][r] += p;
      }
    }
  __syncthreads();   // all bit-reads done before Psum scratch reuses LDS

  // 3) reduce over the 16 lr-lanes, then across the 2 wc waves via LDS
  float* sc = (float*)lds_;
#pragma unroll
  for (int mf = 0; mf < 4; ++mf)
#pragma unroll
    for (int r = 0; r < 4; ++r) {
      float s = rsum[mf][r];
      s += __shfl_xor(s, 1); s += __shfl_xor(s, 2);
      s += __shfl_xor(s, 4); s += __shfl_xor(s, 8);
      if (lr == 0) sc[(wr * 64 + mf * 16 + r4 + r) * 2 + wc] = s;
    }
  __syncthreads();
  if (tid < 128) {
    float tot = sc[tid * 2] + sc[tid * 2 + 1];
    Psum[((long)bz * S_ + arow0 + tid) * 16 + bx] = tot;
  }
}

// ---------------------------------------------------------------------------
extern "C" void kernel_launch(void* const* d_in, const int* in_sizes, int n_in,
                              void* d_out, int out_size, void* d_ws, size_t ws_size,
                              hipStream_t stream) {
  const float* q    = (const float*)d_in[0];
  const float* k    = (const float*)d_in[1];
  const float* v    = (const float*)d_in[2];
  const int*   mask = (const int*)d_in[3];
  const float* Wq   = (const float*)d_in[4];
  const float* bq   = (const float*)d_in[5];
  const float* Wk   = (const float*)d_in[6];
  const float* bk   = (const float*)d_in[7];
  const float* Wv   = (const float*)d_in[8];
  const float* bv   = (const float*)d_in[9];
  const float* Wo   = (const float*)d_in[10];
  const float* bo   = (const float*)d_in[11];

  const long BS = (long)B_ * S_;      // 8192
  const long nQ = BS * DH;            // 8,388,608
  const long nW = (long)DH * DIN;     // 1,048,576
  const long nE = (long)B_ * S_ * S_; // 16,777,216

  char* ws = (char*)d_ws;
  size_t off = 0;
  auto alloc = [&](size_t bytes) {
    void* p = ws + off; off += (bytes + 255) & ~(size_t)255; return p;
  };

  u16* wqb  = (u16*)alloc(4 * nW * 2);       // wq|wk|wv|wo contiguous
  u16* Qb   = (u16*)alloc(nQ * 2);           // Qb,Kbf contiguous (z-batch)
  u16* Kbf  = (u16*)alloc(nQ * 2);
  u16* VT   = (u16*)alloc(nQ * 2);           // V^T written by proj directly
  u16* P    = (u16*)alloc(nE * 2);           // exp(e) unnormalized, bf16
  u64* pk   = (u64*)alloc(nE / 8);           // packed mask bits (2MB)
  float* Psum = (float*)alloc(BS * 16 * 4);  // per-block row partials
  u16* Yb   = (u16*)alloc(nQ * 2);           // attention output
  u16* wob  = wqb + 3 * nW;

  // 1. merged prep: weight cast + mask pack (one launch)
  prep<<<dim3(20480), 256, 0, stream>>>(Wq, Wk, Wv, Wo, wqb, mask, pk);

  // 2. QKV projections, z=3, A staged from fp32; bz==2 writes V^T directly:
  //    grid 8x64x3 = 1536
  gemm97f<<<dim3(1536), 256, 0, stream>>>(q, k, v, wqb, Qb, VT, bq, bk, bv,
      (int)BS, DH, DIN, nW, nQ, 8, 64);

  // 3. P = exp((Q K^T)/32) masked->0 + row partials: grid 16x16x4 = 1024
  pexp128<<<dim3(1024), 256, 0, stream>>>(Qb, Kbf, P, (const u32*)pk, Psum);

  // 4. Y = (P @ V) / rowsum == P[S,S] @ VT[DH,S]^T: grid 8x16x4 = 512
  gemm97<EPI_BF16_ROWSCALE><<<dim3(512), 256, 0, stream>>>(P, VT, Yb,
      nullptr, Psum, S_, DH, S_,
      (long)S_ * S_, (long)DH * S_, (long)S_ * DH, 8, 16);

  // 5. out = Y @ Wo^T + bo -> fp32 d_out: grid 8x64 = 512
  gemm97<EPI_F32_BIAS><<<dim3(512), 256, 0, stream>>>(Yb, wob, d_out,
      bo, nullptr, (int)BS, DOUT, DH, 0, 0, 0, 8, 64);
}